// Round 8
// baseline (258.356 us; speedup 1.0000x reference)
//
#include <hip/hip_runtime.h>
#include <math.h>

// Problem constants (fixed by the reference)
#define BB   2
#define SS   2304
#define DINC 1024
#define DIMC 1024
#define HH   16
#define HD   64

typedef _Float16 half_t;
typedef __attribute__((ext_vector_type(4))) _Float16 half4;   // 2 VGPRs
typedef __attribute__((ext_vector_type(8))) _Float16 half8;   // 4 VGPRs
typedef __attribute__((ext_vector_type(4))) float    f32x4;   // 4 VGPRs

#define LOG2E 1.44269504088896340736f
#define EXP2(x) __builtin_amdgcn_exp2f(x)     // raw v_exp_f32, no libm guard path

// async global->LDS, 16B per lane; LDS dest = wave-uniform base + lane*16
#define GLOAD_LDS16(gp, lp)                                                     \
    __builtin_amdgcn_global_load_lds(                                           \
        (const __attribute__((address_space(1))) void*)(gp),                    \
        (__attribute__((address_space(3))) void*)(lp), 16, 0, 0)

// ---------------------------------------------------------------------------
// Converter: fp32 row-major [R][K] -> f16 tile-blocked [R/RB][K/32][RB][32].
// ---------------------------------------------------------------------------
template<int RB>
__global__ __launch_bounds__(256)
void convert_tile_f16(const float* __restrict__ src, half_t* __restrict__ dst, int K)
{
    constexpr int EPT = RB * 32 / 256;       // elements per thread (16 or 8)
    const int mb = blockIdx.x;
    const int kb = blockIdx.y;
    const int t  = threadIdx.x;
    const int e0 = t * EPT;
    const int mm = e0 >> 5;
    const int kk = e0 & 31;
    const float* sp = src + (size_t)(mb * RB + mm) * K + kb * 32 + kk;
    half_t*      dp = dst + ((size_t)mb * (K >> 5) + kb) * (RB * 32) + mm * 32 + kk;
    #pragma unroll
    for (int g = 0; g < EPT / 4; ++g) {
        float4 v = *(const float4*)(sp + 4 * g);
        dp[4 * g + 0] = (half_t)v.x; dp[4 * g + 1] = (half_t)v.y;
        dp[4 * g + 2] = (half_t)v.z; dp[4 * g + 3] = (half_t)v.w;
    }
}

// ---------------------------------------------------------------------------
// f16 MFMA GEMM (NT): C[m][n] = sum_k A[m][k]*W[n][k] + bias[n], fp32 accum.
// (unchanged)
// ---------------------------------------------------------------------------
template<int BN, bool OUT_HALF>
__global__ __launch_bounds__(256)
void gemm_mfma(const half_t* __restrict__ Ah, const half_t* __restrict__ Bh,
               const float* __restrict__ bias, void* __restrict__ Cout,
               int M, int N, int K)
{
    constexpr int MT = (BN == 128) ? 4 : 2;
    constexpr int NT = 4;
    const int KB = K >> 5;
    __shared__ half_t As[8192];          // [u][128][32]
    __shared__ half_t Bs[2 * BN * 32];   // [u][BN][32]

    const int t    = threadIdx.x;
    const int w    = t >> 6;
    const int lane = t & 63;
    const int l15  = lane & 15, quad = lane >> 4;
    const int wr   = (BN == 128) ? (w >> 1) : w;
    const int wc   = (BN == 128) ? (w & 1) : 0;
    const int mb   = blockIdx.y, nb = blockIdx.x;

    f32x4 acc[MT][NT];
    #pragma unroll
    for (int mt = 0; mt < MT; ++mt)
        #pragma unroll
        for (int nt = 0; nt < NT; ++nt) acc[mt][nt] = (f32x4){0.f, 0.f, 0.f, 0.f};

    const half_t* atile = Ah + (size_t)mb * KB * 4096;
    const half_t* btile = Bh + (size_t)nb * KB * (BN * 32);

    for (int kb = 0; kb < KB; kb += 2) {
        #pragma unroll
        for (int u = 0; u < 2; ++u) {
            const half_t* at = atile + (size_t)(kb + u) * 4096;
            const half_t* bt = btile + (size_t)(kb + u) * (BN * 32);
            #pragma unroll
            for (int v = 0; v < 2; ++v) {
                const int ch = w * 2 + v;
                GLOAD_LDS16(at + ch * 512 + lane * 8, As + u * 4096 + ch * 512);
            }
            if (BN == 128) {
                #pragma unroll
                for (int v = 0; v < 2; ++v) {
                    const int ch = w * 2 + v;
                    GLOAD_LDS16(bt + ch * 512 + lane * 8, Bs + u * 4096 + ch * 512);
                }
            } else {
                GLOAD_LDS16(bt + w * 512 + lane * 8, Bs + u * (BN * 32) + w * 512);
            }
        }
        __syncthreads();

        #pragma unroll
        for (int u = 0; u < 2; ++u) {
            half8 af[MT], bf[NT];
            #pragma unroll
            for (int mt = 0; mt < MT; ++mt)
                af[mt] = *(const half8*)(As + u * 4096
                                         + (wr * (MT * 16) + mt * 16 + l15) * 32 + quad * 8);
            #pragma unroll
            for (int nt = 0; nt < NT; ++nt)
                bf[nt] = *(const half8*)(Bs + u * (BN * 32)
                                         + (wc * 64 + nt * 16 + l15) * 32 + quad * 8);
            #pragma unroll
            for (int mt = 0; mt < MT; ++mt)
                #pragma unroll
                for (int nt = 0; nt < NT; ++nt)
                    acc[mt][nt] = __builtin_amdgcn_mfma_f32_16x16x32_f16(
                        af[mt], bf[nt], acc[mt][nt], 0, 0, 0);
        }
        __syncthreads();
    }

    const int bm = mb * 128, bn = nb * BN;
    #pragma unroll
    for (int nt = 0; nt < NT; ++nt) {
        const int n  = bn + wc * 64 + nt * 16 + l15;
        const float bv = bias[n];
        #pragma unroll
        for (int mt = 0; mt < MT; ++mt) {
            const int m0 = bm + wr * (MT * 16) + mt * 16 + quad * 4;
            #pragma unroll
            for (int rg = 0; rg < 4; ++rg) {
                const float v = acc[mt][nt][rg] + bv;
                if (OUT_HALF) ((half_t*)Cout)[(size_t)(m0 + rg) * N + n] = (half_t)v;
                else          ((float*) Cout)[(size_t)(m0 + rg) * N + n] = v;
            }
        }
    }
}

// ---------------------------------------------------------------------------
// RMSNorm (full 1024) + axial 2D RoPE on the f16 qkv buffer (fp32 math).
// Kf/Vf layouts for the 32-token-chunk, K=32-PV attention (unchanged from v7):
//   chunk c = s>>5 (72 per bh), slot = s&31 within chunk.
//   K slot mapping: tile = (slot>>2)&1, row = 4*(slot>>3)+(slot&3)
//   V: native 16x16x32 A-operand per dt (d = dt*16 + m, k = slot)
//   => softmax outputs {scA[0..3],scB[0..3]} at lane quad q' are exactly
//      slots 8q'..8q'+7, i.e. a contiguous half8 B-operand for K=32 PV.
// ---------------------------------------------------------------------------
__global__ __launch_bounds__(256)
void normrope_v7(half_t* __restrict__ qkvh, const float* __restrict__ q_scale,
                 const float* __restrict__ k_scale, const int* __restrict__ wptr,
                 half_t* __restrict__ Kf, half_t* __restrict__ Vf)
{
    const int token = blockIdx.x;        // b*SS + s
    const int s     = token % SS;
    const int b     = token / SS;
    const int w     = *wptr;
    const int t     = threadIdx.x;
    const float rowp = (float)(s / w);
    const float colp = (float)(s % w);

    half_t* base = qkvh + (size_t)token * 3072;

    const int c    = s >> 5;             // 32-token chunk
    const int slot = s & 31;
    const int ktile = (slot >> 2) & 1;
    const int krow  = ((slot >> 3) << 2) + (slot & 3);

    // ---- V -> Vf (16x16x32 A-operand tiles, k = slot) ----
    {
        half4 v4 = *(const half4*)(base + 2048 + 4 * t);
        const int dabs0 = 4 * t;
        const int h  = dabs0 >> 6;
        const int sl3 = slot >> 3, sl7 = slot & 7;
        half_t* vdst = Vf + ((size_t)(b * HH + h) * 72 + c) * 2048;
        #pragma unroll
        for (int ii = 0; ii < 4; ++ii) {
            const int d = (dabs0 + ii) & 63;
            vdst[(d >> 4) * 512 + (sl3 * 16 + (d & 15)) * 8 + sl7] = v4[ii];
        }
    }

    __shared__ float buf[DIMC];
    __shared__ float red[4];

    #pragma unroll
    for (int sel = 0; sel < 2; ++sel) {
        half_t* row = base + sel * DIMC;
        const float* scp = sel ? k_scale : q_scale;

        half4 xh = *(const half4*)(row + 4 * t);
        float x0 = (float)xh[0], x1 = (float)xh[1], x2 = (float)xh[2], x3 = (float)xh[3];
        float ss = x0 * x0 + x1 * x1 + x2 * x2 + x3 * x3;
        #pragma unroll
        for (int o = 32; o >= 1; o >>= 1) ss += __shfl_xor(ss, o);
        if ((t & 63) == 0) red[t >> 6] = ss;
        __syncthreads();

        const float rinv = rsqrtf((red[0] + red[1] + red[2] + red[3]) * (1.0f / DIMC) + 1e-6f);
        float4 g = *(const float4*)(scp + 4 * t);
        buf[4 * t + 0] = x0 * rinv * g.x;
        buf[4 * t + 1] = x1 * rinv * g.y;
        buf[4 * t + 2] = x2 * rinv * g.z;
        buf[4 * t + 3] = x3 * rinv * g.w;
        __syncthreads();

        const float qsc = sel ? 1.0f : (0.125f * LOG2E);  // log2-domain scores

        #pragma unroll
        for (int pp = 0; pp < 2; ++pp) {
            const int p = t + pp * 256;
            const int h = p >> 5;
            const int r = p & 31;
            const int j = r & 15;
            const float pos = (r < 16) ? rowp : colp;
            const int d1 = (r < 16) ? j : (32 + j);   // within-head dim
            const int d2 = d1 + 16;
            const float freq = exp2f((float)j * -0.83048202372f);
            const float ang  = pos * freq;
            float sn, cs;
            __sincosf(ang, &sn, &cs);
            const float a1 = buf[h * HD + d1], a2 = buf[h * HD + d2];
            const float o1 = (a1 * cs - a2 * sn) * qsc;
            const float o2 = (a2 * cs + a1 * sn) * qsc;
            if (sel == 0) {
                row[h * HD + d1] = (half_t)o1;
                row[h * HD + d2] = (half_t)o2;
            } else {
                half_t* kdst = Kf + ((size_t)(b * HH + h) * 72 + c) * 2048;
                kdst[((ktile << 1) + (d1 >> 5)) * 512
                     + ((((d1 & 31) >> 3) << 4) + krow) * 8 + (d1 & 7)] = (half_t)o1;
                kdst[((ktile << 1) + (d2 >> 5)) * 512
                     + ((((d2 & 31) >> 3) << 4) + krow) * 8 + (d2 & 7)] = (half_t)o2;
            }
        }
        __syncthreads();   // buf/red reused by next sel
    }
}

// ---------------------------------------------------------------------------
// Flash attention v15: v12's compute with a REGISTER DIET to break the
// TWO-ROUND dispatch quantization.
// Evidence (r3-r7): OccupancyPercent ~28-30 on every variant = exactly
// (16 waves + 2 waves)/2: grid = capacity*1.125 -> a full 16-wave/CU round
// plus a ~empty straggler round; makespan 2*T_block vs ideal 1.125*T_block.
// Residency capped at 16 waves/CU by unified VGPR+AGPR ~104-112/wave
// (512/112 = 4 waves/SIMD). Fix: fit 5 waves/SIMD (<=102 regs) so capacity
// becomes 5 blocks/CU = 1280 >= 1152 -> SINGLE ROUND.
// Diet: (a) K and V share ONE 16-reg buffer set: QK reads it as K, then V(p)
// loads into the same regs (covered by softmax's ~200cyc VALU chain), PV
// reads it as V, then K(p+1) loads (exposed ~backedge; 20 waves/CU TLP
// absorbs); (b) scalar l accumulators; (c) __launch_bounds__(256,5).
// Revert criteria: WRITE_SIZE > 9.3MB (spill) or occupancy stuck at ~28.
// ---------------------------------------------------------------------------
__global__ __launch_bounds__(256, 5)
void flash_attn_mfma15(const half_t* __restrict__ qkvh, const half_t* __restrict__ Kf,
                       const half_t* __restrict__ Vf, half_t* __restrict__ attn_h)
{
    const int flat = blockIdx.x;         // 0..1151, XCD-swizzled
    const int xcd  = flat & 7;
    const int idx  = flat >> 3;          // 0..143  (144 per XCD = exactly 4 bh)
    const int bh   = xcd * 4 + idx / 36;
    const int qtb  = idx % 36;
    const int b    = bh >> 4, h = bh & 15;
    const int t    = threadIdx.x;
    const int w    = t >> 6;
    const int qh   = w >> 1;             // wave's q-half (32 rows)
    const int jt   = w & 1;              // wave's chunk parity
    const int lane = t & 63;
    const int l15  = lane & 15, quad = lane >> 4;

    const size_t tb = (size_t)b * SS;
    const int q0 = qtb * 64;

    __shared__ float mlb[4][32];         // per-wave l for its 32 q's
    __shared__ float Ob[2][64][33];      // [qh][d][q], padded stride 33

    // Q B-frags (loop invariant): B[k=quad*8+i][n=l15], 2 q-tiles x 2 d-groups
    half8 qf[2][2];
    #pragma unroll
    for (int qt = 0; qt < 2; ++qt)
        #pragma unroll
        for (int dg = 0; dg < 2; ++dg)
            qf[qt][dg] = *(const half8*)(qkvh + (tb + q0 + qh * 32 + qt * 16 + l15) * 3072
                                          + h * HD + dg * 32 + quad * 8);

    f32x4 acc[4][2];                     // [dt][qt] : O^T[dt*16+quad*4+reg][q]
    float lacc[2] = {0.f, 0.f};          // scalar l accumulator per qt
    #pragma unroll
    for (int qt = 0; qt < 2; ++qt)
        #pragma unroll
        for (int dt = 0; dt < 4; ++dt) acc[dt][qt] = (f32x4){0.f, 0.f, 0.f, 0.f};

    // wave's chunk pointers: wave-chunk p -> global chunk (2p + jt)
    const half_t* kpl = Kf + (size_t)bh * 147456 + jt * 2048 + lane * 8;
    const half_t* vpl = Vf + (size_t)bh * 147456 + jt * 2048 + lane * 8;

    // shared K/V buffer set (16 regs): starts as K(0)
    half8 kv0 = *(const half8*)(kpl);
    half8 kv1 = *(const half8*)(kpl + 512);
    half8 kv2 = *(const half8*)(kpl + 1024);
    half8 kv3 = *(const half8*)(kpl + 1536);

    const f32x4 initC = (f32x4){-4.f, -4.f, -4.f, -4.f};   // P = exp2(s - 4)

    for (int p = 0; p < 36; ++p) {
        // ---- S^T both 16-row tiles (kv = K(p); dead after issue) ----
        f32x4 scA[2], scB[2];
        __builtin_amdgcn_s_setprio(1);
        #pragma unroll
        for (int qt = 0; qt < 2; ++qt) {
            scA[qt] = initC;
            scA[qt] = __builtin_amdgcn_mfma_f32_16x16x32_f16(kv0, qf[qt][0], scA[qt], 0, 0, 0);
            scA[qt] = __builtin_amdgcn_mfma_f32_16x16x32_f16(kv1, qf[qt][1], scA[qt], 0, 0, 0);
            scB[qt] = initC;
            scB[qt] = __builtin_amdgcn_mfma_f32_16x16x32_f16(kv2, qf[qt][0], scB[qt], 0, 0, 0);
            scB[qt] = __builtin_amdgcn_mfma_f32_16x16x32_f16(kv3, qf[qt][1], scB[qt], 0, 0, 0);
        }
        __builtin_amdgcn_s_setprio(0);

        // ---- V(p) into the shared buffer (use-distance = softmax chain) ----
        {
            const half_t* vN = vpl + (size_t)p * 4096;
            kv0 = *(const half8*)(vN);
            kv1 = *(const half8*)(vN + 512);
            kv2 = *(const half8*)(vN + 1024);
            kv3 = *(const half8*)(vN + 1536);
        }

        // ---- no-max softmax: P = exp2(s-4) directly, scalar l ----
        half8 pf[2];
        #pragma unroll
        for (int qt = 0; qt < 2; ++qt) {
            const float a0 = EXP2(scA[qt][0]);
            const float a1 = EXP2(scA[qt][1]);
            const float a2 = EXP2(scA[qt][2]);
            const float a3 = EXP2(scA[qt][3]);
            const float b0 = EXP2(scB[qt][0]);
            const float b1 = EXP2(scB[qt][1]);
            const float b2 = EXP2(scB[qt][2]);
            const float b3 = EXP2(scB[qt][3]);
            lacc[qt] += ((a0 + a1) + (a2 + a3)) + ((b0 + b1) + (b2 + b3));
            // lane quad q' holds P for slots 8q'..8q'+7 -> contiguous B-frag
            pf[qt] = (half8){(half_t)a0, (half_t)a1, (half_t)a2, (half_t)a3,
                             (half_t)b0, (half_t)b1, (half_t)b2, (half_t)b3};
        }

        // ---- O^T += V^T . P^T (kv = V(p)) ----
        __builtin_amdgcn_s_setprio(1);
        #pragma unroll
        for (int dt = 0; dt < 4; ++dt) {
            const half8 vf = (dt == 0) ? kv0 : (dt == 1) ? kv1 : (dt == 2) ? kv2 : kv3;
            #pragma unroll
            for (int qt = 0; qt < 2; ++qt)
                acc[dt][qt] = __builtin_amdgcn_mfma_f32_16x16x32_f16(
                    vf, pf[qt], acc[dt][qt], 0, 0, 0);
        }
        __builtin_amdgcn_s_setprio(0);

        // ---- K(p+1) into the shared buffer ----
        if (p + 1 < 36) {
            const half_t* kN = kpl + (size_t)(p + 1) * 4096;
            kv0 = *(const half8*)(kN);
            kv1 = *(const half8*)(kN + 512);
            kv2 = *(const half8*)(kN + 1024);
            kv3 = *(const half8*)(kN + 1536);
        }
    }

    // ---- 2-way merge across jt waves, per q-half ----
    #pragma unroll
    for (int qt = 0; qt < 2; ++qt) {      // cross-quad reduce lane-local l
        float lq = lacc[qt];
        lq += __shfl_xor(lq, 16);
        lq += __shfl_xor(lq, 32);
        if (quad == 0) mlb[w][qt * 16 + l15] = lq;
    }
    __syncthreads();

    float fac[2];
    #pragma unroll
    for (int qt = 0; qt < 2; ++qt) {
        const int q = qt * 16 + l15;
        fac[qt] = 1.0f / (mlb[qh * 2 + 0][q] + mlb[qh * 2 + 1][q]);
    }

    #pragma unroll
    for (int ph = 0; ph < 2; ++ph) {
        if (jt == ph) {
            #pragma unroll
            for (int dt = 0; dt < 4; ++dt)
                #pragma unroll
                for (int qt = 0; qt < 2; ++qt)
                    #pragma unroll
                    for (int rg = 0; rg < 4; ++rg) {
                        const int d = dt * 16 + quad * 4 + rg;
                        const int q = qt * 16 + l15;
                        const float v = acc[dt][qt][rg] * fac[qt];
                        if (ph == 0) Ob[qh][d][q] = v;
                        else         Ob[qh][d][q] += v;
                    }
        }
        __syncthreads();
    }

    // ---- store O as f16, tile-blocked [mb][kb][128][32] for the proj GEMM ----
    {
        const int q   = t >> 2;              // token within q-tile (0..63)
        const int ds  = (t & 3) * 16;
        const int qh2 = q >> 5, qq = q & 31;
        const size_t mrow = tb + q0 + q;
        const int mb2 = (int)(mrow >> 7);
        const int mm  = (int)(mrow & 127);
        #pragma unroll
        for (int g = 0; g < 4; ++g) {
            const int dd = ds + 4 * g;
            const int kb2 = (h * HD + dd) >> 5;
            const int kk  = dd & 31;
            half4 o;
            o[0] = (half_t)Ob[qh2][dd + 0][qq];
            o[1] = (half_t)Ob[qh2][dd + 1][qq];
            o[2] = (half_t)Ob[qh2][dd + 2][qq];
            o[3] = (half_t)Ob[qh2][dd + 3][qq];
            *(half4*)(attn_h + ((size_t)mb2 * 32 + kb2) * 4096 + mm * 32 + kk) = o;
        }
    }
}

// ---------------------------------------------------------------------------
// Launch
// ---------------------------------------------------------------------------
extern "C" void kernel_launch(void* const* d_in, const int* in_sizes, int n_in,
                              void* d_out, int out_size, void* d_ws, size_t ws_size,
                              hipStream_t stream)
{
    const float* input   = (const float*)d_in[0];
    const float* qkv_w   = (const float*)d_in[1];
    const float* qkv_b   = (const float*)d_in[2];
    const float* q_scale = (const float*)d_in[3];
    const float* k_scale = (const float*)d_in[4];
    const float* proj_w  = (const float*)d_in[5];
    const float* proj_b  = (const float*)d_in[6];
    const int*   width   = (const int*)d_in[8];
    float* out = (float*)d_out;

    // ws layout (all f16): qkv_h 28.3MB | attn_h 9.4 | Vf 9.4 | Ah 9.4 (reused
    // as Kf after GEMM1) | Bh1 6.3 | Bh2 2.1  => 65.0 MB total
    half_t* qkvh   = (half_t*)d_ws;
    half_t* attn_h = qkvh   + (size_t)4608 * 3072;
    half_t* Vf     = attn_h + (size_t)4608 * 1024;
    half_t* Ah     = Vf     + (size_t)32 * 72 * 2048;
    half_t* Bh1    = Ah     + (size_t)4608 * 1024;
    half_t* Bh2    = Bh1    + (size_t)3072 * 1024;
    half_t* Kf     = Ah;    // Ah is dead after GEMM1; Kf is written by normrope

    const int M = BB * SS;   // 4608

    // 0) fp32 -> f16 tile-blocked converters (proj_w 64-row-blocked)
    convert_tile_f16<128><<<dim3(M / 128, DINC / 32),        256, 0, stream>>>(input,  Ah,  DINC);
    convert_tile_f16<128><<<dim3(3 * DIMC / 128, DINC / 32), 256, 0, stream>>>(qkv_w, Bh1, DINC);
    convert_tile_f16<64><<<dim3(DINC / 64, DIMC / 32),       256, 0, stream>>>(proj_w, Bh2, DIMC);

    // 1) qkv_h = f16( input @ qkv_w^T + qkv_b )
    gemm_mfma<128, true><<<dim3(3 * DIMC / 128, M / 128), 256, 0, stream>>>(
        Ah, Bh1, qkv_b, qkvh, M, 3 * DIMC, DINC);

    // 2) RMSNorm + RoPE: Q in place (log2-scaled), K -> Kf, V -> Vf
    normrope_v7<<<M, 256, 0, stream>>>(qkvh, q_scale, k_scale, width, Kf, Vf);

    // 3) MFMA flash attention -> attn_h (f16, tile-blocked), XCD-swizzled
    flash_attn_mfma15<<<dim3(1152), 256, 0, stream>>>(qkvh, Kf, Vf, attn_h);

    // 4) out = attn @ proj_w^T + proj_b  (fp32 out, BN=64 for occupancy)
    gemm_mfma<64, false><<<dim3(DINC / 64, M / 128), 256, 0, stream>>>(
        attn_h, Bh2, proj_b, out, M, DINC, DIMC);
}

// Round 9
// 240.290 us; speedup vs baseline: 1.0752x; 1.0752x over previous
//
#include <hip/hip_runtime.h>
#include <math.h>

// Problem constants (fixed by the reference)
#define BB   2
#define SS   2304
#define DINC 1024
#define DIMC 1024
#define HH   16
#define HD   64

typedef _Float16 half_t;
typedef __attribute__((ext_vector_type(4))) _Float16 half4;   // 2 VGPRs
typedef __attribute__((ext_vector_type(8))) _Float16 half8;   // 4 VGPRs
typedef __attribute__((ext_vector_type(4))) float    f32x4;   // 4 VGPRs

#define LOG2E 1.44269504088896340736f
#define EXP2(x) __builtin_amdgcn_exp2f(x)     // raw v_exp_f32, no libm guard path

// async global->LDS, 16B per lane; LDS dest = wave-uniform base + lane*16
#define GLOAD_LDS16(gp, lp)                                                     \
    __builtin_amdgcn_global_load_lds(                                           \
        (const __attribute__((address_space(1))) void*)(gp),                    \
        (__attribute__((address_space(3))) void*)(lp), 16, 0, 0)

// ---------------------------------------------------------------------------
// Converter: fp32 row-major [R][K] -> f16 tile-blocked [R/RB][K/32][RB][32].
// ---------------------------------------------------------------------------
template<int RB>
__global__ __launch_bounds__(256)
void convert_tile_f16(const float* __restrict__ src, half_t* __restrict__ dst, int K)
{
    constexpr int EPT = RB * 32 / 256;       // elements per thread (16 or 8)
    const int mb = blockIdx.x;
    const int kb = blockIdx.y;
    const int t  = threadIdx.x;
    const int e0 = t * EPT;
    const int mm = e0 >> 5;
    const int kk = e0 & 31;
    const float* sp = src + (size_t)(mb * RB + mm) * K + kb * 32 + kk;
    half_t*      dp = dst + ((size_t)mb * (K >> 5) + kb) * (RB * 32) + mm * 32 + kk;
    #pragma unroll
    for (int g = 0; g < EPT / 4; ++g) {
        float4 v = *(const float4*)(sp + 4 * g);
        dp[4 * g + 0] = (half_t)v.x; dp[4 * g + 1] = (half_t)v.y;
        dp[4 * g + 2] = (half_t)v.z; dp[4 * g + 3] = (half_t)v.w;
    }
}

// ---------------------------------------------------------------------------
// f16 MFMA GEMM (NT): C[m][n] = sum_k A[m][k]*W[n][k] + bias[n], fp32 accum.
// (unchanged)
// ---------------------------------------------------------------------------
template<int BN, bool OUT_HALF>
__global__ __launch_bounds__(256)
void gemm_mfma(const half_t* __restrict__ Ah, const half_t* __restrict__ Bh,
               const float* __restrict__ bias, void* __restrict__ Cout,
               int M, int N, int K)
{
    constexpr int MT = (BN == 128) ? 4 : 2;
    constexpr int NT = 4;
    const int KB = K >> 5;
    __shared__ half_t As[8192];          // [u][128][32]
    __shared__ half_t Bs[2 * BN * 32];   // [u][BN][32]

    const int t    = threadIdx.x;
    const int w    = t >> 6;
    const int lane = t & 63;
    const int l15  = lane & 15, quad = lane >> 4;
    const int wr   = (BN == 128) ? (w >> 1) : w;
    const int wc   = (BN == 128) ? (w & 1) : 0;
    const int mb   = blockIdx.y, nb = blockIdx.x;

    f32x4 acc[MT][NT];
    #pragma unroll
    for (int mt = 0; mt < MT; ++mt)
        #pragma unroll
        for (int nt = 0; nt < NT; ++nt) acc[mt][nt] = (f32x4){0.f, 0.f, 0.f, 0.f};

    const half_t* atile = Ah + (size_t)mb * KB * 4096;
    const half_t* btile = Bh + (size_t)nb * KB * (BN * 32);

    for (int kb = 0; kb < KB; kb += 2) {
        #pragma unroll
        for (int u = 0; u < 2; ++u) {
            const half_t* at = atile + (size_t)(kb + u) * 4096;
            const half_t* bt = btile + (size_t)(kb + u) * (BN * 32);
            #pragma unroll
            for (int v = 0; v < 2; ++v) {
                const int ch = w * 2 + v;
                GLOAD_LDS16(at + ch * 512 + lane * 8, As + u * 4096 + ch * 512);
            }
            if (BN == 128) {
                #pragma unroll
                for (int v = 0; v < 2; ++v) {
                    const int ch = w * 2 + v;
                    GLOAD_LDS16(bt + ch * 512 + lane * 8, Bs + u * 4096 + ch * 512);
                }
            } else {
                GLOAD_LDS16(bt + w * 512 + lane * 8, Bs + u * (BN * 32) + w * 512);
            }
        }
        __syncthreads();

        #pragma unroll
        for (int u = 0; u < 2; ++u) {
            half8 af[MT], bf[NT];
            #pragma unroll
            for (int mt = 0; mt < MT; ++mt)
                af[mt] = *(const half8*)(As + u * 4096
                                         + (wr * (MT * 16) + mt * 16 + l15) * 32 + quad * 8);
            #pragma unroll
            for (int nt = 0; nt < NT; ++nt)
                bf[nt] = *(const half8*)(Bs + u * (BN * 32)
                                         + (wc * 64 + nt * 16 + l15) * 32 + quad * 8);
            #pragma unroll
            for (int mt = 0; mt < MT; ++mt)
                #pragma unroll
                for (int nt = 0; nt < NT; ++nt)
                    acc[mt][nt] = __builtin_amdgcn_mfma_f32_16x16x32_f16(
                        af[mt], bf[nt], acc[mt][nt], 0, 0, 0);
        }
        __syncthreads();
    }

    const int bm = mb * 128, bn = nb * BN;
    #pragma unroll
    for (int nt = 0; nt < NT; ++nt) {
        const int n  = bn + wc * 64 + nt * 16 + l15;
        const float bv = bias[n];
        #pragma unroll
        for (int mt = 0; mt < MT; ++mt) {
            const int m0 = bm + wr * (MT * 16) + mt * 16 + quad * 4;
            #pragma unroll
            for (int rg = 0; rg < 4; ++rg) {
                const float v = acc[mt][nt][rg] + bv;
                if (OUT_HALF) ((half_t*)Cout)[(size_t)(m0 + rg) * N + n] = (half_t)v;
                else          ((float*) Cout)[(size_t)(m0 + rg) * N + n] = v;
            }
        }
    }
}

// ---------------------------------------------------------------------------
// RMSNorm (full 1024) + axial 2D RoPE on the f16 qkv buffer (fp32 math).
// Kf/Vf layouts for the 32-token-chunk, K=32-PV attention (unchanged from v7):
//   chunk c = s>>5 (72 per bh), slot = s&31 within chunk.
//   K slot mapping: tile = (slot>>2)&1, row = 4*(slot>>3)+(slot&3)
//   V: native 16x16x32 A-operand per dt (d = dt*16 + m, k = slot)
//   => softmax outputs {scA[0..3],scB[0..3]} at lane quad q' are exactly
//      slots 8q'..8q'+7, i.e. a contiguous half8 B-operand for K=32 PV.
// ---------------------------------------------------------------------------
__global__ __launch_bounds__(256)
void normrope_v7(half_t* __restrict__ qkvh, const float* __restrict__ q_scale,
                 const float* __restrict__ k_scale, const int* __restrict__ wptr,
                 half_t* __restrict__ Kf, half_t* __restrict__ Vf)
{
    const int token = blockIdx.x;        // b*SS + s
    const int s     = token % SS;
    const int b     = token / SS;
    const int w     = *wptr;
    const int t     = threadIdx.x;
    const float rowp = (float)(s / w);
    const float colp = (float)(s % w);

    half_t* base = qkvh + (size_t)token * 3072;

    const int c    = s >> 5;             // 32-token chunk
    const int slot = s & 31;
    const int ktile = (slot >> 2) & 1;
    const int krow  = ((slot >> 3) << 2) + (slot & 3);

    // ---- V -> Vf (16x16x32 A-operand tiles, k = slot) ----
    {
        half4 v4 = *(const half4*)(base + 2048 + 4 * t);
        const int dabs0 = 4 * t;
        const int h  = dabs0 >> 6;
        const int sl3 = slot >> 3, sl7 = slot & 7;
        half_t* vdst = Vf + ((size_t)(b * HH + h) * 72 + c) * 2048;
        #pragma unroll
        for (int ii = 0; ii < 4; ++ii) {
            const int d = (dabs0 + ii) & 63;
            vdst[(d >> 4) * 512 + (sl3 * 16 + (d & 15)) * 8 + sl7] = v4[ii];
        }
    }

    __shared__ float buf[DIMC];
    __shared__ float red[4];

    #pragma unroll
    for (int sel = 0; sel < 2; ++sel) {
        half_t* row = base + sel * DIMC;
        const float* scp = sel ? k_scale : q_scale;

        half4 xh = *(const half4*)(row + 4 * t);
        float x0 = (float)xh[0], x1 = (float)xh[1], x2 = (float)xh[2], x3 = (float)xh[3];
        float ss = x0 * x0 + x1 * x1 + x2 * x2 + x3 * x3;
        #pragma unroll
        for (int o = 32; o >= 1; o >>= 1) ss += __shfl_xor(ss, o);
        if ((t & 63) == 0) red[t >> 6] = ss;
        __syncthreads();

        const float rinv = rsqrtf((red[0] + red[1] + red[2] + red[3]) * (1.0f / DIMC) + 1e-6f);
        float4 g = *(const float4*)(scp + 4 * t);
        buf[4 * t + 0] = x0 * rinv * g.x;
        buf[4 * t + 1] = x1 * rinv * g.y;
        buf[4 * t + 2] = x2 * rinv * g.z;
        buf[4 * t + 3] = x3 * rinv * g.w;
        __syncthreads();

        const float qsc = sel ? 1.0f : (0.125f * LOG2E);  // log2-domain scores

        #pragma unroll
        for (int pp = 0; pp < 2; ++pp) {
            const int p = t + pp * 256;
            const int h = p >> 5;
            const int r = p & 31;
            const int j = r & 15;
            const float pos = (r < 16) ? rowp : colp;
            const int d1 = (r < 16) ? j : (32 + j);   // within-head dim
            const int d2 = d1 + 16;
            const float freq = exp2f((float)j * -0.83048202372f);
            const float ang  = pos * freq;
            float sn, cs;
            __sincosf(ang, &sn, &cs);
            const float a1 = buf[h * HD + d1], a2 = buf[h * HD + d2];
            const float o1 = (a1 * cs - a2 * sn) * qsc;
            const float o2 = (a2 * cs + a1 * sn) * qsc;
            if (sel == 0) {
                row[h * HD + d1] = (half_t)o1;
                row[h * HD + d2] = (half_t)o2;
            } else {
                half_t* kdst = Kf + ((size_t)(b * HH + h) * 72 + c) * 2048;
                kdst[((ktile << 1) + (d1 >> 5)) * 512
                     + ((((d1 & 31) >> 3) << 4) + krow) * 8 + (d1 & 7)] = (half_t)o1;
                kdst[((ktile << 1) + (d2 >> 5)) * 512
                     + ((((d2 & 31) >> 3) << 4) + krow) * 8 + (d2 & 7)] = (half_t)o2;
            }
        }
        __syncthreads();   // buf/red reused by next sel
    }
}

// ---------------------------------------------------------------------------
// Flash attention v16: v12's inner loop with a 96-ROW Q-TILE so the grid
// divides the machine EXACTLY (no two-round quantization, no register diet).
// Evidence: r3-r7 all show OccupancyPercent ~28 = (16-wave round + 2-wave
// straggler round)/2 -- grid 1152 = 4.5 blocks/CU vs 4 resident. r8's diet
// raised occupancy to 39 (theory confirmed) but spilled (WRITE_SIZE +8MB).
// Fix: q-tile 96 -> 24 q-tiles x 32 bh = 768 blocks = EXACTLY 3 blocks/CU
// (and 96/XCD = exactly 4 bh -> swizzle preserved). Each wave owns 48 q rows
// (qt in {0,1,2}); registers ~+36 vs v12 (~160 total) within the 170-reg
// budget of launch_bounds(256,3). Makespan: 1 x T_block(96) ~ 1.4 x
// T_block(64) vs v12's 2 x T_block(64). Inner loop/softmax/layouts identical.
// Revert criteria: WRITE_SIZE > 9.3MB (spill) or occupancy < 30.
// ---------------------------------------------------------------------------
__global__ __launch_bounds__(256, 3)
void flash_attn_mfma16(const half_t* __restrict__ qkvh, const half_t* __restrict__ Kf,
                       const half_t* __restrict__ Vf, half_t* __restrict__ attn_h)
{
    const int flat = blockIdx.x;         // 0..767, XCD-swizzled
    const int xcd  = flat & 7;
    const int idx  = flat >> 3;          // 0..95  (96 per XCD = exactly 4 bh)
    const int bh   = xcd * 4 + idx / 24;
    const int qtb  = idx % 24;
    const int b    = bh >> 4, h = bh & 15;
    const int t    = threadIdx.x;
    const int w    = t >> 6;
    const int qh   = w >> 1;             // wave's q-half (48 rows)
    const int jt   = w & 1;              // wave's chunk parity
    const int lane = t & 63;
    const int l15  = lane & 15, quad = lane >> 4;

    const size_t tb = (size_t)b * SS;
    const int q0 = qtb * 96;

    __shared__ float mlb[4][48];         // per-wave l for its 48 q's
    __shared__ float Ob[2][64][49];      // [qh][d][q(48)], padded stride 49

    // Q B-frags (loop invariant): B[k=quad*8+i][n=l15], 3 q-tiles x 2 d-groups
    half8 qf[3][2];
    #pragma unroll
    for (int qt = 0; qt < 3; ++qt)
        #pragma unroll
        for (int dg = 0; dg < 2; ++dg)
            qf[qt][dg] = *(const half8*)(qkvh + (tb + q0 + qh * 48 + qt * 16 + l15) * 3072
                                          + h * HD + dg * 32 + quad * 8);

    f32x4 acc[4][3];                     // [dt][qt] : O^T[dt*16+quad*4+reg][q]
    float lacc[3] = {0.f, 0.f, 0.f};     // scalar l accumulator per qt
    #pragma unroll
    for (int qt = 0; qt < 3; ++qt)
        #pragma unroll
        for (int dt = 0; dt < 4; ++dt) acc[dt][qt] = (f32x4){0.f, 0.f, 0.f, 0.f};

    // wave's chunk pointers: wave-chunk p -> global chunk (2p + jt)
    const half_t* kpl = Kf + (size_t)bh * 147456 + jt * 2048 + lane * 8;
    const half_t* vpl = Vf + (size_t)bh * 147456 + jt * 2048 + lane * 8;

    // initial chunk (separate K and V buffers, v12's proven pattern)
    half8 k00 = *(const half8*)(kpl);            // tile0, d 0..31
    half8 k01 = *(const half8*)(kpl + 512);      // tile0, d 32..63
    half8 k10 = *(const half8*)(kpl + 1024);     // tile1, d 0..31
    half8 k11 = *(const half8*)(kpl + 1536);     // tile1, d 32..63
    half8 v0  = *(const half8*)(vpl);            // dt A-frags (k=slot)
    half8 v1  = *(const half8*)(vpl + 512);
    half8 v2  = *(const half8*)(vpl + 1024);
    half8 v3  = *(const half8*)(vpl + 1536);

    const f32x4 initC = (f32x4){-4.f, -4.f, -4.f, -4.f};   // P = exp2(s - 4)

    for (int p = 0; p < 36; ++p) {
        // ---- S^T both 16-row tiles x 3 q-tiles (k regs dead afterwards) ----
        f32x4 scA[3], scB[3];
        __builtin_amdgcn_s_setprio(1);
        #pragma unroll
        for (int qt = 0; qt < 3; ++qt) {
            scA[qt] = initC;
            scA[qt] = __builtin_amdgcn_mfma_f32_16x16x32_f16(k00, qf[qt][0], scA[qt], 0, 0, 0);
            scA[qt] = __builtin_amdgcn_mfma_f32_16x16x32_f16(k01, qf[qt][1], scA[qt], 0, 0, 0);
            scB[qt] = initC;
            scB[qt] = __builtin_amdgcn_mfma_f32_16x16x32_f16(k10, qf[qt][0], scB[qt], 0, 0, 0);
            scB[qt] = __builtin_amdgcn_mfma_f32_16x16x32_f16(k11, qf[qt][1], scB[qt], 0, 0, 0);
        }
        __builtin_amdgcn_s_setprio(0);

        // ---- prefetch next chunk's K into the now-dead k regs ----
        if (p + 1 < 36) {
            const half_t* kN = kpl + (size_t)(p + 1) * 4096;
            k00 = *(const half8*)(kN);
            k01 = *(const half8*)(kN + 512);
            k10 = *(const half8*)(kN + 1024);
            k11 = *(const half8*)(kN + 1536);
        }

        // ---- no-max softmax: P = exp2(s-4) directly, scalar l ----
        half8 pf[3];
        #pragma unroll
        for (int qt = 0; qt < 3; ++qt) {
            const float a0 = EXP2(scA[qt][0]);
            const float a1 = EXP2(scA[qt][1]);
            const float a2 = EXP2(scA[qt][2]);
            const float a3 = EXP2(scA[qt][3]);
            const float b0 = EXP2(scB[qt][0]);
            const float b1 = EXP2(scB[qt][1]);
            const float b2 = EXP2(scB[qt][2]);
            const float b3 = EXP2(scB[qt][3]);
            lacc[qt] += ((a0 + a1) + (a2 + a3)) + ((b0 + b1) + (b2 + b3));
            // lane quad q' holds P for slots 8q'..8q'+7 -> contiguous B-frag
            pf[qt] = (half8){(half_t)a0, (half_t)a1, (half_t)a2, (half_t)a3,
                             (half_t)b0, (half_t)b1, (half_t)b2, (half_t)b3};
        }

        // ---- O^T += V^T . P^T, single K=32 pass (v regs dead afterwards) ----
        __builtin_amdgcn_s_setprio(1);
        #pragma unroll
        for (int dt = 0; dt < 4; ++dt) {
            const half8 vf = (dt == 0) ? v0 : (dt == 1) ? v1 : (dt == 2) ? v2 : v3;
            #pragma unroll
            for (int qt = 0; qt < 3; ++qt)
                acc[dt][qt] = __builtin_amdgcn_mfma_f32_16x16x32_f16(
                    vf, pf[qt], acc[dt][qt], 0, 0, 0);
        }
        __builtin_amdgcn_s_setprio(0);

        // ---- prefetch next chunk's V into the now-dead v regs ----
        if (p + 1 < 36) {
            const half_t* vN = vpl + (size_t)(p + 1) * 4096;
            v0 = *(const half8*)(vN);
            v1 = *(const half8*)(vN + 512);
            v2 = *(const half8*)(vN + 1024);
            v3 = *(const half8*)(vN + 1536);
        }
    }

    // ---- 2-way merge across jt waves, per q-half ----
    #pragma unroll
    for (int qt = 0; qt < 3; ++qt) {      // cross-quad reduce lane-local l
        float lq = lacc[qt];
        lq += __shfl_xor(lq, 16);
        lq += __shfl_xor(lq, 32);
        if (quad == 0) mlb[w][qt * 16 + l15] = lq;
    }
    __syncthreads();

    float fac[3];
    #pragma unroll
    for (int qt = 0; qt < 3; ++qt) {
        const int q = qt * 16 + l15;
        fac[qt] = 1.0f / (mlb[qh * 2 + 0][q] + mlb[qh * 2 + 1][q]);
    }

    #pragma unroll
    for (int ph = 0; ph < 2; ++ph) {
        if (jt == ph) {
            #pragma unroll
            for (int dt = 0; dt < 4; ++dt)
                #pragma unroll
                for (int qt = 0; qt < 3; ++qt)
                    #pragma unroll
                    for (int rg = 0; rg < 4; ++rg) {
                        const int d = dt * 16 + quad * 4 + rg;
                        const int q = qt * 16 + l15;
                        const float v = acc[dt][qt][rg] * fac[qt];
                        if (ph == 0) Ob[qh][d][q] = v;
                        else         Ob[qh][d][q] += v;
                    }
        }
        __syncthreads();
    }

    // ---- store O as f16, tile-blocked [mb][kb][128][32] for the proj GEMM ----
    // 96 rows x 64 d = 6144 halfs; 3 groups of 32 rows, 8 threads/row x 8 d.
    #pragma unroll
    for (int g2 = 0; g2 < 3; ++g2) {
        const int q  = g2 * 32 + (t >> 3);   // 0..95
        const int ds = (t & 7) * 8;          // 0..56, 8-aligned
        const int qh2 = (q >= 48) ? 1 : 0;
        const int qq  = q - 48 * qh2;
        const size_t mrow = tb + q0 + q;
        const int mb2 = (int)(mrow >> 7);
        const int mm  = (int)(mrow & 127);
        const int kb2 = (h * HD + ds) >> 5;
        const int kk  = ds & 31;
        half8 o;
        #pragma unroll
        for (int ii = 0; ii < 8; ++ii) o[ii] = (half_t)Ob[qh2][ds + ii][qq];
        *(half8*)(attn_h + ((size_t)mb2 * 32 + kb2) * 4096 + mm * 32 + kk) = o;
    }
}

// ---------------------------------------------------------------------------
// Launch
// ---------------------------------------------------------------------------
extern "C" void kernel_launch(void* const* d_in, const int* in_sizes, int n_in,
                              void* d_out, int out_size, void* d_ws, size_t ws_size,
                              hipStream_t stream)
{
    const float* input   = (const float*)d_in[0];
    const float* qkv_w   = (const float*)d_in[1];
    const float* qkv_b   = (const float*)d_in[2];
    const float* q_scale = (const float*)d_in[3];
    const float* k_scale = (const float*)d_in[4];
    const float* proj_w  = (const float*)d_in[5];
    const float* proj_b  = (const float*)d_in[6];
    const int*   width   = (const int*)d_in[8];
    float* out = (float*)d_out;

    // ws layout (all f16): qkv_h 28.3MB | attn_h 9.4 | Vf 9.4 | Ah 9.4 (reused
    // as Kf after GEMM1) | Bh1 6.3 | Bh2 2.1  => 65.0 MB total
    half_t* qkvh   = (half_t*)d_ws;
    half_t* attn_h = qkvh   + (size_t)4608 * 3072;
    half_t* Vf     = attn_h + (size_t)4608 * 1024;
    half_t* Ah     = Vf     + (size_t)32 * 72 * 2048;
    half_t* Bh1    = Ah     + (size_t)4608 * 1024;
    half_t* Bh2    = Bh1    + (size_t)3072 * 1024;
    half_t* Kf     = Ah;    // Ah is dead after GEMM1; Kf is written by normrope

    const int M = BB * SS;   // 4608

    // 0) fp32 -> f16 tile-blocked converters (proj_w 64-row-blocked)
    convert_tile_f16<128><<<dim3(M / 128, DINC / 32),        256, 0, stream>>>(input,  Ah,  DINC);
    convert_tile_f16<128><<<dim3(3 * DIMC / 128, DINC / 32), 256, 0, stream>>>(qkv_w, Bh1, DINC);
    convert_tile_f16<64><<<dim3(DINC / 64, DIMC / 32),       256, 0, stream>>>(proj_w, Bh2, DIMC);

    // 1) qkv_h = f16( input @ qkv_w^T + qkv_b )
    gemm_mfma<128, true><<<dim3(3 * DIMC / 128, M / 128), 256, 0, stream>>>(
        Ah, Bh1, qkv_b, qkvh, M, 3 * DIMC, DINC);

    // 2) RMSNorm + RoPE: Q in place (log2-scaled), K -> Kf, V -> Vf
    normrope_v7<<<M, 256, 0, stream>>>(qkvh, q_scale, k_scale, width, Kf, Vf);

    // 3) MFMA flash attention -> attn_h (f16, tile-blocked), XCD-swizzled
    flash_attn_mfma16<<<dim3(768), 256, 0, stream>>>(qkvh, Kf, Vf, attn_h);

    // 4) out = attn @ proj_w^T + proj_b  (fp32 out, BN=64 for occupancy)
    gemm_mfma<64, false><<<dim3(DINC / 64, M / 128), 256, 0, stream>>>(
        attn_h, Bh2, proj_b, out, M, DINC, DIMC);
}

// Round 10
// 231.033 us; speedup vs baseline: 1.1183x; 1.0401x over previous
//
#include <hip/hip_runtime.h>
#include <math.h>

// Problem constants (fixed by the reference)
#define BB   2
#define SS   2304
#define DINC 1024
#define DIMC 1024
#define HH   16
#define HD   64

typedef _Float16 half_t;
typedef __attribute__((ext_vector_type(4))) _Float16 half4;   // 2 VGPRs
typedef __attribute__((ext_vector_type(8))) _Float16 half8;   // 4 VGPRs
typedef __attribute__((ext_vector_type(4))) float    f32x4;   // 4 VGPRs

#define LOG2E 1.44269504088896340736f
#define EXP2(x) __builtin_amdgcn_exp2f(x)     // raw v_exp_f32, no libm guard path

// async global->LDS, 16B per lane; LDS dest = wave-uniform base + lane*16
#define GLOAD_LDS16(gp, lp)                                                     \
    __builtin_amdgcn_global_load_lds(                                           \
        (const __attribute__((address_space(1))) void*)(gp),                    \
        (__attribute__((address_space(3))) void*)(lp), 16, 0, 0)

// ---------------------------------------------------------------------------
// Converter: fp32 row-major [R][K] -> f16 tile-blocked [R/RB][K/32][RB][32].
// Rewritten for arbitrary RB: element-flat indexing, per-group row recompute
// (the old per-thread pointer arithmetic assumed a thread's elements never
// cross a 32-col row boundary -- only true for RB in {64,128}).
// ---------------------------------------------------------------------------
template<int RB>
__global__ __launch_bounds__(256)
void convert_tile_f16(const float* __restrict__ src, half_t* __restrict__ dst, int K)
{
    constexpr int NG = RB * 32 / 1024;       // groups of 1024 elements
    const int mb = blockIdx.x;
    const int kb = blockIdx.y;
    const int t  = threadIdx.x;
    const float* sp0 = src + (size_t)mb * RB * K + kb * 32;
    half_t*      dp0 = dst + ((size_t)mb * (K >> 5) + kb) * (RB * 32);
    #pragma unroll
    for (int g = 0; g < NG; ++g) {
        const int e  = g * 1024 + t * 4;     // flat element in [RB][32] tile
        const int mm = e >> 5, kk = e & 31;
        float4 v = *(const float4*)(sp0 + (size_t)mm * K + kk);
        dp0[e + 0] = (half_t)v.x; dp0[e + 1] = (half_t)v.y;
        dp0[e + 2] = (half_t)v.z; dp0[e + 3] = (half_t)v.w;
    }
}

// ---------------------------------------------------------------------------
// GEMM1: 192x96-tile f16 MFMA GEMM (NT), fixed shape M=4608 N=3072 K=1024.
// Evidence (r9): the 128x128 version ran 864 blocks at capacity 3/CU
// (152 unified regs/wave) -> full 768-block round + 96-block straggler round,
// OccupancyPercent 16, dur 51us. Re-tile: 24 x 32 = 768 blocks = EXACTLY
// 3 blocks/CU, single round. 4 waves in 2x2; per-wave 96x48 = acc[6][3]
// (72 AGPR, ~130 unified -> capacity 3 preserved). A blocked [24][32][192][32]
// (RB=192 converter), B blocked [32][32][96][32] (RB=96). Same 2-barrier
// double-buffered global_load_lds staging as before (18 chunks/u split
// round-robin across 4 waves).
// ---------------------------------------------------------------------------
__global__ __launch_bounds__(256, 3)
void gemm_mfma192(const half_t* __restrict__ Ah, const half_t* __restrict__ Bh,
                  const float* __restrict__ bias, half_t* __restrict__ Cout)
{
    const int t    = threadIdx.x;
    const int w    = t >> 6;
    const int lane = t & 63;
    const int l15  = lane & 15, quad = lane >> 4;
    const int wr   = w >> 1;             // 0,1 : row half (96 rows)
    const int wc   = w & 1;              // 0,1 : col half (48 cols)
    const int mb   = blockIdx.y;         // 0..23
    const int nb   = blockIdx.x;         // 0..31

    __shared__ __align__(16) half_t As[2][6144];   // [u][192][32] = 24 KB
    __shared__ __align__(16) half_t Bs[2][3072];   // [u][96][32]  = 12 KB

    f32x4 acc[6][3];
    #pragma unroll
    for (int mt = 0; mt < 6; ++mt)
        #pragma unroll
        for (int nt = 0; nt < 3; ++nt) acc[mt][nt] = (f32x4){0.f, 0.f, 0.f, 0.f};

    const half_t* atile = Ah + (size_t)mb * 32 * 6144;
    const half_t* btile = Bh + (size_t)nb * 32 * 3072;

    for (int kb = 0; kb < 32; kb += 2) {
        #pragma unroll
        for (int u = 0; u < 2; ++u) {
            const half_t* at = atile + (size_t)(kb + u) * 6144;
            const half_t* bt = btile + (size_t)(kb + u) * 3072;
            // 18 chunks of 512 halfs (12 A + 6 B), round-robin over 4 waves
            for (int ch = w; ch < 18; ch += 4) {
                if (ch < 12) GLOAD_LDS16(at + ch * 512 + lane * 8, &As[u][ch * 512]);
                else         GLOAD_LDS16(bt + (ch - 12) * 512 + lane * 8,
                                         &Bs[u][(ch - 12) * 512]);
            }
        }
        __syncthreads();

        #pragma unroll
        for (int u = 0; u < 2; ++u) {
            half8 af[6], bf[3];
            #pragma unroll
            for (int mt = 0; mt < 6; ++mt)
                af[mt] = *(const half8*)(&As[u][(wr * 96 + mt * 16 + l15) * 32 + quad * 8]);
            #pragma unroll
            for (int nt = 0; nt < 3; ++nt)
                bf[nt] = *(const half8*)(&Bs[u][(wc * 48 + nt * 16 + l15) * 32 + quad * 8]);
            #pragma unroll
            for (int mt = 0; mt < 6; ++mt)
                #pragma unroll
                for (int nt = 0; nt < 3; ++nt)
                    acc[mt][nt] = __builtin_amdgcn_mfma_f32_16x16x32_f16(
                        af[mt], bf[nt], acc[mt][nt], 0, 0, 0);
        }
        __syncthreads();
    }

    const int bm = mb * 192, bn = nb * 96;
    #pragma unroll
    for (int nt = 0; nt < 3; ++nt) {
        const int n  = bn + wc * 48 + nt * 16 + l15;
        const float bv = bias[n];
        #pragma unroll
        for (int mt = 0; mt < 6; ++mt) {
            const int m0 = bm + wr * 96 + mt * 16 + quad * 4;
            #pragma unroll
            for (int rg = 0; rg < 4; ++rg)
                Cout[(size_t)(m0 + rg) * 3072 + n] = (half_t)(acc[mt][nt][rg] + bv);
        }
    }
}

// ---------------------------------------------------------------------------
// GEMM2: f16 MFMA GEMM (NT): C[m][n] = sum_k A[m][k]*W[n][k] + bias[n].
// (128x64 tile, fp32 out -- unchanged; 576 blocks, low regs, single round.)
// ---------------------------------------------------------------------------
template<int BN, bool OUT_HALF>
__global__ __launch_bounds__(256)
void gemm_mfma(const half_t* __restrict__ Ah, const half_t* __restrict__ Bh,
               const float* __restrict__ bias, void* __restrict__ Cout,
               int M, int N, int K)
{
    constexpr int MT = (BN == 128) ? 4 : 2;
    constexpr int NT = 4;
    const int KB = K >> 5;
    __shared__ half_t As[8192];          // [u][128][32]
    __shared__ half_t Bs[2 * BN * 32];   // [u][BN][32]

    const int t    = threadIdx.x;
    const int w    = t >> 6;
    const int lane = t & 63;
    const int l15  = lane & 15, quad = lane >> 4;
    const int wr   = (BN == 128) ? (w >> 1) : w;
    const int wc   = (BN == 128) ? (w & 1) : 0;
    const int mb   = blockIdx.y, nb = blockIdx.x;

    f32x4 acc[MT][NT];
    #pragma unroll
    for (int mt = 0; mt < MT; ++mt)
        #pragma unroll
        for (int nt = 0; nt < NT; ++nt) acc[mt][nt] = (f32x4){0.f, 0.f, 0.f, 0.f};

    const half_t* atile = Ah + (size_t)mb * KB * 4096;
    const half_t* btile = Bh + (size_t)nb * KB * (BN * 32);

    for (int kb = 0; kb < KB; kb += 2) {
        #pragma unroll
        for (int u = 0; u < 2; ++u) {
            const half_t* at = atile + (size_t)(kb + u) * 4096;
            const half_t* bt = btile + (size_t)(kb + u) * (BN * 32);
            #pragma unroll
            for (int v = 0; v < 2; ++v) {
                const int ch = w * 2 + v;
                GLOAD_LDS16(at + ch * 512 + lane * 8, As + u * 4096 + ch * 512);
            }
            GLOAD_LDS16(bt + w * 512 + lane * 8, Bs + u * (BN * 32) + w * 512);
        }
        __syncthreads();

        #pragma unroll
        for (int u = 0; u < 2; ++u) {
            half8 af[MT], bf[NT];
            #pragma unroll
            for (int mt = 0; mt < MT; ++mt)
                af[mt] = *(const half8*)(As + u * 4096
                                         + (wr * (MT * 16) + mt * 16 + l15) * 32 + quad * 8);
            #pragma unroll
            for (int nt = 0; nt < NT; ++nt)
                bf[nt] = *(const half8*)(Bs + u * (BN * 32)
                                         + (wc * 64 + nt * 16 + l15) * 32 + quad * 8);
            #pragma unroll
            for (int mt = 0; mt < MT; ++mt)
                #pragma unroll
                for (int nt = 0; nt < NT; ++nt)
                    acc[mt][nt] = __builtin_amdgcn_mfma_f32_16x16x32_f16(
                        af[mt], bf[nt], acc[mt][nt], 0, 0, 0);
        }
        __syncthreads();
    }

    const int bm = mb * 128, bn = nb * BN;
    #pragma unroll
    for (int nt = 0; nt < NT; ++nt) {
        const int n  = bn + wc * 64 + nt * 16 + l15;
        const float bv = bias[n];
        #pragma unroll
        for (int mt = 0; mt < MT; ++mt) {
            const int m0 = bm + wr * (MT * 16) + mt * 16 + quad * 4;
            #pragma unroll
            for (int rg = 0; rg < 4; ++rg) {
                const float v = acc[mt][nt][rg] + bv;
                if (OUT_HALF) ((half_t*)Cout)[(size_t)(m0 + rg) * N + n] = (half_t)v;
                else          ((float*) Cout)[(size_t)(m0 + rg) * N + n] = v;
            }
        }
    }
}

// ---------------------------------------------------------------------------
// RMSNorm (full 1024) + axial 2D RoPE on the f16 qkv buffer (fp32 math).
// Kf/Vf layouts for the 32-token-chunk, K=32-PV attention (unchanged from v7):
//   chunk c = s>>5 (72 per bh), slot = s&31 within chunk.
//   K slot mapping: tile = (slot>>2)&1, row = 4*(slot>>3)+(slot&3)
//   V: native 16x16x32 A-operand per dt (d = dt*16 + m, k = slot)
//   => softmax outputs {scA[0..3],scB[0..3]} at lane quad q' are exactly
//      slots 8q'..8q'+7, i.e. a contiguous half8 B-operand for K=32 PV.
// ---------------------------------------------------------------------------
__global__ __launch_bounds__(256)
void normrope_v7(half_t* __restrict__ qkvh, const float* __restrict__ q_scale,
                 const float* __restrict__ k_scale, const int* __restrict__ wptr,
                 half_t* __restrict__ Kf, half_t* __restrict__ Vf)
{
    const int token = blockIdx.x;        // b*SS + s
    const int s     = token % SS;
    const int b     = token / SS;
    const int w     = *wptr;
    const int t     = threadIdx.x;
    const float rowp = (float)(s / w);
    const float colp = (float)(s % w);

    half_t* base = qkvh + (size_t)token * 3072;

    const int c    = s >> 5;             // 32-token chunk
    const int slot = s & 31;
    const int ktile = (slot >> 2) & 1;
    const int krow  = ((slot >> 3) << 2) + (slot & 3);

    // ---- V -> Vf (16x16x32 A-operand tiles, k = slot) ----
    {
        half4 v4 = *(const half4*)(base + 2048 + 4 * t);
        const int dabs0 = 4 * t;
        const int h  = dabs0 >> 6;
        const int sl3 = slot >> 3, sl7 = slot & 7;
        half_t* vdst = Vf + ((size_t)(b * HH + h) * 72 + c) * 2048;
        #pragma unroll
        for (int ii = 0; ii < 4; ++ii) {
            const int d = (dabs0 + ii) & 63;
            vdst[(d >> 4) * 512 + (sl3 * 16 + (d & 15)) * 8 + sl7] = v4[ii];
        }
    }

    __shared__ float buf[DIMC];
    __shared__ float red[4];

    #pragma unroll
    for (int sel = 0; sel < 2; ++sel) {
        half_t* row = base + sel * DIMC;
        const float* scp = sel ? k_scale : q_scale;

        half4 xh = *(const half4*)(row + 4 * t);
        float x0 = (float)xh[0], x1 = (float)xh[1], x2 = (float)xh[2], x3 = (float)xh[3];
        float ss = x0 * x0 + x1 * x1 + x2 * x2 + x3 * x3;
        #pragma unroll
        for (int o = 32; o >= 1; o >>= 1) ss += __shfl_xor(ss, o);
        if ((t & 63) == 0) red[t >> 6] = ss;
        __syncthreads();

        const float rinv = rsqrtf((red[0] + red[1] + red[2] + red[3]) * (1.0f / DIMC) + 1e-6f);
        float4 g = *(const float4*)(scp + 4 * t);
        buf[4 * t + 0] = x0 * rinv * g.x;
        buf[4 * t + 1] = x1 * rinv * g.y;
        buf[4 * t + 2] = x2 * rinv * g.z;
        buf[4 * t + 3] = x3 * rinv * g.w;
        __syncthreads();

        const float qsc = sel ? 1.0f : (0.125f * LOG2E);  // log2-domain scores

        #pragma unroll
        for (int pp = 0; pp < 2; ++pp) {
            const int p = t + pp * 256;
            const int h = p >> 5;
            const int r = p & 31;
            const int j = r & 15;
            const float pos = (r < 16) ? rowp : colp;
            const int d1 = (r < 16) ? j : (32 + j);   // within-head dim
            const int d2 = d1 + 16;
            const float freq = exp2f((float)j * -0.83048202372f);
            const float ang  = pos * freq;
            float sn, cs;
            __sincosf(ang, &sn, &cs);
            const float a1 = buf[h * HD + d1], a2 = buf[h * HD + d2];
            const float o1 = (a1 * cs - a2 * sn) * qsc;
            const float o2 = (a2 * cs + a1 * sn) * qsc;
            if (sel == 0) {
                row[h * HD + d1] = (half_t)o1;
                row[h * HD + d2] = (half_t)o2;
            } else {
                half_t* kdst = Kf + ((size_t)(b * HH + h) * 72 + c) * 2048;
                kdst[((ktile << 1) + (d1 >> 5)) * 512
                     + ((((d1 & 31) >> 3) << 4) + krow) * 8 + (d1 & 7)] = (half_t)o1;
                kdst[((ktile << 1) + (d2 >> 5)) * 512
                     + ((((d2 & 31) >> 3) << 4) + krow) * 8 + (d2 & 7)] = (half_t)o2;
            }
        }
        __syncthreads();   // buf/red reused by next sel
    }
}

// ---------------------------------------------------------------------------
// Flash attention v16 (r9, PROVEN): 96-row q-tile, 768 blocks = exactly 3/CU,
// no-max softmax, K=32 PV, distance-1 dead-register prefetch. Unchanged.
// ---------------------------------------------------------------------------
__global__ __launch_bounds__(256, 3)
void flash_attn_mfma16(const half_t* __restrict__ qkvh, const half_t* __restrict__ Kf,
                       const half_t* __restrict__ Vf, half_t* __restrict__ attn_h)
{
    const int flat = blockIdx.x;         // 0..767, XCD-swizzled
    const int xcd  = flat & 7;
    const int idx  = flat >> 3;          // 0..95  (96 per XCD = exactly 4 bh)
    const int bh   = xcd * 4 + idx / 24;
    const int qtb  = idx % 24;
    const int b    = bh >> 4, h = bh & 15;
    const int t    = threadIdx.x;
    const int w    = t >> 6;
    const int qh   = w >> 1;             // wave's q-half (48 rows)
    const int jt   = w & 1;              // wave's chunk parity
    const int lane = t & 63;
    const int l15  = lane & 15, quad = lane >> 4;

    const size_t tb = (size_t)b * SS;
    const int q0 = qtb * 96;

    __shared__ float mlb[4][48];         // per-wave l for its 48 q's
    __shared__ float Ob[2][64][49];      // [qh][d][q(48)], padded stride 49

    // Q B-frags (loop invariant): B[k=quad*8+i][n=l15], 3 q-tiles x 2 d-groups
    half8 qf[3][2];
    #pragma unroll
    for (int qt = 0; qt < 3; ++qt)
        #pragma unroll
        for (int dg = 0; dg < 2; ++dg)
            qf[qt][dg] = *(const half8*)(qkvh + (tb + q0 + qh * 48 + qt * 16 + l15) * 3072
                                          + h * HD + dg * 32 + quad * 8);

    f32x4 acc[4][3];                     // [dt][qt] : O^T[dt*16+quad*4+reg][q]
    float lacc[3] = {0.f, 0.f, 0.f};     // scalar l accumulator per qt
    #pragma unroll
    for (int qt = 0; qt < 3; ++qt)
        #pragma unroll
        for (int dt = 0; dt < 4; ++dt) acc[dt][qt] = (f32x4){0.f, 0.f, 0.f, 0.f};

    // wave's chunk pointers: wave-chunk p -> global chunk (2p + jt)
    const half_t* kpl = Kf + (size_t)bh * 147456 + jt * 2048 + lane * 8;
    const half_t* vpl = Vf + (size_t)bh * 147456 + jt * 2048 + lane * 8;

    // initial chunk (separate K and V buffers)
    half8 k00 = *(const half8*)(kpl);            // tile0, d 0..31
    half8 k01 = *(const half8*)(kpl + 512);      // tile0, d 32..63
    half8 k10 = *(const half8*)(kpl + 1024);     // tile1, d 0..31
    half8 k11 = *(const half8*)(kpl + 1536);     // tile1, d 32..63
    half8 v0  = *(const half8*)(vpl);            // dt A-frags (k=slot)
    half8 v1  = *(const half8*)(vpl + 512);
    half8 v2  = *(const half8*)(vpl + 1024);
    half8 v3  = *(const half8*)(vpl + 1536);

    const f32x4 initC = (f32x4){-4.f, -4.f, -4.f, -4.f};   // P = exp2(s - 4)

    for (int p = 0; p < 36; ++p) {
        // ---- S^T both 16-row tiles x 3 q-tiles (k regs dead afterwards) ----
        f32x4 scA[3], scB[3];
        __builtin_amdgcn_s_setprio(1);
        #pragma unroll
        for (int qt = 0; qt < 3; ++qt) {
            scA[qt] = initC;
            scA[qt] = __builtin_amdgcn_mfma_f32_16x16x32_f16(k00, qf[qt][0], scA[qt], 0, 0, 0);
            scA[qt] = __builtin_amdgcn_mfma_f32_16x16x32_f16(k01, qf[qt][1], scA[qt], 0, 0, 0);
            scB[qt] = initC;
            scB[qt] = __builtin_amdgcn_mfma_f32_16x16x32_f16(k10, qf[qt][0], scB[qt], 0, 0, 0);
            scB[qt] = __builtin_amdgcn_mfma_f32_16x16x32_f16(k11, qf[qt][1], scB[qt], 0, 0, 0);
        }
        __builtin_amdgcn_s_setprio(0);

        // ---- prefetch next chunk's K into the now-dead k regs ----
        if (p + 1 < 36) {
            const half_t* kN = kpl + (size_t)(p + 1) * 4096;
            k00 = *(const half8*)(kN);
            k01 = *(const half8*)(kN + 512);
            k10 = *(const half8*)(kN + 1024);
            k11 = *(const half8*)(kN + 1536);
        }

        // ---- no-max softmax: P = exp2(s-4) directly, scalar l ----
        half8 pf[3];
        #pragma unroll
        for (int qt = 0; qt < 3; ++qt) {
            const float a0 = EXP2(scA[qt][0]);
            const float a1 = EXP2(scA[qt][1]);
            const float a2 = EXP2(scA[qt][2]);
            const float a3 = EXP2(scA[qt][3]);
            const float b0 = EXP2(scB[qt][0]);
            const float b1 = EXP2(scB[qt][1]);
            const float b2 = EXP2(scB[qt][2]);
            const float b3 = EXP2(scB[qt][3]);
            lacc[qt] += ((a0 + a1) + (a2 + a3)) + ((b0 + b1) + (b2 + b3));
            // lane quad q' holds P for slots 8q'..8q'+7 -> contiguous B-frag
            pf[qt] = (half8){(half_t)a0, (half_t)a1, (half_t)a2, (half_t)a3,
                             (half_t)b0, (half_t)b1, (half_t)b2, (half_t)b3};
        }

        // ---- O^T += V^T . P^T, single K=32 pass (v regs dead afterwards) ----
        __builtin_amdgcn_s_setprio(1);
        #pragma unroll
        for (int dt = 0; dt < 4; ++dt) {
            const half8 vf = (dt == 0) ? v0 : (dt == 1) ? v1 : (dt == 2) ? v2 : v3;
            #pragma unroll
            for (int qt = 0; qt < 3; ++qt)
                acc[dt][qt] = __builtin_amdgcn_mfma_f32_16x16x32_f16(
                    vf, pf[qt], acc[dt][qt], 0, 0, 0);
        }
        __builtin_amdgcn_s_setprio(0);

        // ---- prefetch next chunk's V into the now-dead v regs ----
        if (p + 1 < 36) {
            const half_t* vN = vpl + (size_t)(p + 1) * 4096;
            v0 = *(const half8*)(vN);
            v1 = *(const half8*)(vN + 512);
            v2 = *(const half8*)(vN + 1024);
            v3 = *(const half8*)(vN + 1536);
        }
    }

    // ---- 2-way merge across jt waves, per q-half ----
    #pragma unroll
    for (int qt = 0; qt < 3; ++qt) {      // cross-quad reduce lane-local l
        float lq = lacc[qt];
        lq += __shfl_xor(lq, 16);
        lq += __shfl_xor(lq, 32);
        if (quad == 0) mlb[w][qt * 16 + l15] = lq;
    }
    __syncthreads();

    float fac[3];
    #pragma unroll
    for (int qt = 0; qt < 3; ++qt) {
        const int q = qt * 16 + l15;
        fac[qt] = 1.0f / (mlb[qh * 2 + 0][q] + mlb[qh * 2 + 1][q]);
    }

    #pragma unroll
    for (int ph = 0; ph < 2; ++ph) {
        if (jt == ph) {
            #pragma unroll
            for (int dt = 0; dt < 4; ++dt)
                #pragma unroll
                for (int qt = 0; qt < 3; ++qt)
                    #pragma unroll
                    for (int rg = 0; rg < 4; ++rg) {
                        const int d = dt * 16 + quad * 4 + rg;
                        const int q = qt * 16 + l15;
                        const float v = acc[dt][qt][rg] * fac[qt];
                        if (ph == 0) Ob[qh][d][q] = v;
                        else         Ob[qh][d][q] += v;
                    }
        }
        __syncthreads();
    }

    // ---- store O as f16, tile-blocked [mb][kb][128][32] for the proj GEMM ----
    // 96 rows x 64 d = 6144 halfs; 3 groups of 32 rows, 8 threads/row x 8 d.
    #pragma unroll
    for (int g2 = 0; g2 < 3; ++g2) {
        const int q  = g2 * 32 + (t >> 3);   // 0..95
        const int ds = (t & 7) * 8;          // 0..56, 8-aligned
        const int qh2 = (q >= 48) ? 1 : 0;
        const int qq  = q - 48 * qh2;
        const size_t mrow = tb + q0 + q;
        const int mb2 = (int)(mrow >> 7);
        const int mm  = (int)(mrow & 127);
        const int kb2 = (h * HD + ds) >> 5;
        const int kk  = ds & 31;
        half8 o;
        #pragma unroll
        for (int ii = 0; ii < 8; ++ii) o[ii] = (half_t)Ob[qh2][ds + ii][qq];
        *(half8*)(attn_h + ((size_t)mb2 * 32 + kb2) * 4096 + mm * 32 + kk) = o;
    }
}

// ---------------------------------------------------------------------------
// Launch
// ---------------------------------------------------------------------------
extern "C" void kernel_launch(void* const* d_in, const int* in_sizes, int n_in,
                              void* d_out, int out_size, void* d_ws, size_t ws_size,
                              hipStream_t stream)
{
    const float* input   = (const float*)d_in[0];
    const float* qkv_w   = (const float*)d_in[1];
    const float* qkv_b   = (const float*)d_in[2];
    const float* q_scale = (const float*)d_in[3];
    const float* k_scale = (const float*)d_in[4];
    const float* proj_w  = (const float*)d_in[5];
    const float* proj_b  = (const float*)d_in[6];
    const int*   width   = (const int*)d_in[8];
    float* out = (float*)d_out;

    // ws layout (all f16): qkv_h 28.3MB | attn_h 9.4 | Vf 9.4 | Ah 9.4 (reused
    // as Kf after GEMM1) | Bh1 6.3 | Bh2 2.1  => 65.0 MB total
    half_t* qkvh   = (half_t*)d_ws;
    half_t* attn_h = qkvh   + (size_t)4608 * 3072;
    half_t* Vf     = attn_h + (size_t)4608 * 1024;
    half_t* Ah     = Vf     + (size_t)32 * 72 * 2048;
    half_t* Bh1    = Ah     + (size_t)4608 * 1024;
    half_t* Bh2    = Bh1    + (size_t)3072 * 1024;
    half_t* Kf     = Ah;    // Ah is dead after GEMM1; Kf is written by normrope

    const int M = BB * SS;   // 4608

    // 0) fp32 -> f16 tile-blocked converters
    //    input -> 192-row blocks (GEMM1 A), qkv_w -> 96-row blocks (GEMM1 B),
    //    proj_w -> 64-row blocks (GEMM2 B)
    convert_tile_f16<192><<<dim3(M / 192, DINC / 32),        256, 0, stream>>>(input,  Ah,  DINC);
    convert_tile_f16<96><<<dim3(3 * DIMC / 96, DINC / 32),   256, 0, stream>>>(qkv_w, Bh1, DINC);
    convert_tile_f16<64><<<dim3(DINC / 64, DIMC / 32),       256, 0, stream>>>(proj_w, Bh2, DIMC);

    // 1) qkv_h = f16( input @ qkv_w^T + qkv_b )  -- 192x96 tiles, 768 blocks
    gemm_mfma192<<<dim3(3 * DIMC / 96, M / 192), 256, 0, stream>>>(
        Ah, Bh1, qkv_b, qkvh);

    // 2) RMSNorm + RoPE: Q in place (log2-scaled), K -> Kf, V -> Vf
    normrope_v7<<<M, 256, 0, stream>>>(qkvh, q_scale, k_scale, width, Kf, Vf);

    // 3) MFMA flash attention -> attn_h (f16, tile-blocked), XCD-swizzled
    flash_attn_mfma16<<<dim3(768), 256, 0, stream>>>(qkvh, Kf, Vf, attn_h);

    // 4) out = attn @ proj_w^T + proj_b  (fp32 out, BN=64 for occupancy)
    gemm_mfma<64, false><<<dim3(DINC / 64, M / 128), 256, 0, stream>>>(
        attn_h, Bh2, proj_b, out, M, DINC, DIMC);
}

// Round 11
// 228.011 us; speedup vs baseline: 1.1331x; 1.0133x over previous
//
#include <hip/hip_runtime.h>
#include <math.h>

// Problem constants (fixed by the reference)
#define BB   2
#define SS   2304
#define DINC 1024
#define DIMC 1024
#define HH   16
#define HD   64

typedef _Float16 half_t;
typedef __attribute__((ext_vector_type(4))) _Float16 half4;   // 2 VGPRs
typedef __attribute__((ext_vector_type(8))) _Float16 half8;   // 4 VGPRs
typedef __attribute__((ext_vector_type(4))) float    f32x4;   // 4 VGPRs

#define LOG2E 1.44269504088896340736f
#define EXP2(x) __builtin_amdgcn_exp2f(x)     // raw v_exp_f32, no libm guard path

// async global->LDS, 16B per lane; LDS dest = wave-uniform base + lane*16
#define GLOAD_LDS16(gp, lp)                                                     \
    __builtin_amdgcn_global_load_lds(                                           \
        (const __attribute__((address_space(1))) void*)(gp),                    \
        (__attribute__((address_space(3))) void*)(lp), 16, 0, 0)

// ---------------------------------------------------------------------------
// Converter: fp32 row-major [R][K] -> f16 tile-blocked [R/RB][K/32][RB][32].
// Element-flat indexing, valid for any RB multiple of 32.
// ---------------------------------------------------------------------------
template<int RB>
__global__ __launch_bounds__(256)
void convert_tile_f16(const float* __restrict__ src, half_t* __restrict__ dst, int K)
{
    constexpr int NG = RB * 32 / 1024;       // groups of 1024 elements
    const int mb = blockIdx.x;
    const int kb = blockIdx.y;
    const int t  = threadIdx.x;
    const float* sp0 = src + (size_t)mb * RB * K + kb * 32;
    half_t*      dp0 = dst + ((size_t)mb * (K >> 5) + kb) * (RB * 32);
    #pragma unroll
    for (int g = 0; g < NG; ++g) {
        const int e  = g * 1024 + t * 4;     // flat element in [RB][32] tile
        const int mm = e >> 5, kk = e & 31;
        float4 v = *(const float4*)(sp0 + (size_t)mm * K + kk);
        dp0[e + 0] = (half_t)v.x; dp0[e + 1] = (half_t)v.y;
        dp0[e + 2] = (half_t)v.z; dp0[e + 3] = (half_t)v.w;
    }
}

// ---------------------------------------------------------------------------
// GEMM1: 192x96-tile f16 MFMA GEMM (NT), fixed shape M=4608 N=3072 K=1024.
// (r10, PROVEN: 768 blocks = exactly 3/CU, single round.) Unchanged.
// ---------------------------------------------------------------------------
__global__ __launch_bounds__(256, 3)
void gemm_mfma192(const half_t* __restrict__ Ah, const half_t* __restrict__ Bh,
                  const float* __restrict__ bias, half_t* __restrict__ Cout)
{
    const int t    = threadIdx.x;
    const int w    = t >> 6;
    const int lane = t & 63;
    const int l15  = lane & 15, quad = lane >> 4;
    const int wr   = w >> 1;             // 0,1 : row half (96 rows)
    const int wc   = w & 1;              // 0,1 : col half (48 cols)
    const int mb   = blockIdx.y;         // 0..23
    const int nb   = blockIdx.x;         // 0..31

    __shared__ __align__(16) half_t As[2][6144];   // [u][192][32] = 24 KB
    __shared__ __align__(16) half_t Bs[2][3072];   // [u][96][32]  = 12 KB

    f32x4 acc[6][3];
    #pragma unroll
    for (int mt = 0; mt < 6; ++mt)
        #pragma unroll
        for (int nt = 0; nt < 3; ++nt) acc[mt][nt] = (f32x4){0.f, 0.f, 0.f, 0.f};

    const half_t* atile = Ah + (size_t)mb * 32 * 6144;
    const half_t* btile = Bh + (size_t)nb * 32 * 3072;

    for (int kb = 0; kb < 32; kb += 2) {
        #pragma unroll
        for (int u = 0; u < 2; ++u) {
            const half_t* at = atile + (size_t)(kb + u) * 6144;
            const half_t* bt = btile + (size_t)(kb + u) * 3072;
            // 18 chunks of 512 halfs (12 A + 6 B), round-robin over 4 waves
            for (int ch = w; ch < 18; ch += 4) {
                if (ch < 12) GLOAD_LDS16(at + ch * 512 + lane * 8, &As[u][ch * 512]);
                else         GLOAD_LDS16(bt + (ch - 12) * 512 + lane * 8,
                                         &Bs[u][(ch - 12) * 512]);
            }
        }
        __syncthreads();

        #pragma unroll
        for (int u = 0; u < 2; ++u) {
            half8 af[6], bf[3];
            #pragma unroll
            for (int mt = 0; mt < 6; ++mt)
                af[mt] = *(const half8*)(&As[u][(wr * 96 + mt * 16 + l15) * 32 + quad * 8]);
            #pragma unroll
            for (int nt = 0; nt < 3; ++nt)
                bf[nt] = *(const half8*)(&Bs[u][(wc * 48 + nt * 16 + l15) * 32 + quad * 8]);
            #pragma unroll
            for (int mt = 0; mt < 6; ++mt)
                #pragma unroll
                for (int nt = 0; nt < 3; ++nt)
                    acc[mt][nt] = __builtin_amdgcn_mfma_f32_16x16x32_f16(
                        af[mt], bf[nt], acc[mt][nt], 0, 0, 0);
        }
        __syncthreads();
    }

    const int bm = mb * 192, bn = nb * 96;
    #pragma unroll
    for (int nt = 0; nt < 3; ++nt) {
        const int n  = bn + wc * 48 + nt * 16 + l15;
        const float bv = bias[n];
        #pragma unroll
        for (int mt = 0; mt < 6; ++mt) {
            const int m0 = bm + wr * 96 + mt * 16 + quad * 4;
            #pragma unroll
            for (int rg = 0; rg < 4; ++rg)
                Cout[(size_t)(m0 + rg) * 3072 + n] = (half_t)(acc[mt][nt][rg] + bv);
        }
    }
}

// ---------------------------------------------------------------------------
// GEMM2: f16 MFMA GEMM (NT): C[m][n] = sum_k A[m][k]*W[n][k] + bias[n].
// (128x64 tile, fp32 out -- unchanged.)
// ---------------------------------------------------------------------------
template<int BN, bool OUT_HALF>
__global__ __launch_bounds__(256)
void gemm_mfma(const half_t* __restrict__ Ah, const half_t* __restrict__ Bh,
               const float* __restrict__ bias, void* __restrict__ Cout,
               int M, int N, int K)
{
    constexpr int MT = (BN == 128) ? 4 : 2;
    constexpr int NT = 4;
    const int KB = K >> 5;
    __shared__ half_t As[8192];          // [u][128][32]
    __shared__ half_t Bs[2 * BN * 32];   // [u][BN][32]

    const int t    = threadIdx.x;
    const int w    = t >> 6;
    const int lane = t & 63;
    const int l15  = lane & 15, quad = lane >> 4;
    const int wr   = (BN == 128) ? (w >> 1) : w;
    const int wc   = (BN == 128) ? (w & 1) : 0;
    const int mb   = blockIdx.y, nb = blockIdx.x;

    f32x4 acc[MT][NT];
    #pragma unroll
    for (int mt = 0; mt < MT; ++mt)
        #pragma unroll
        for (int nt = 0; nt < NT; ++nt) acc[mt][nt] = (f32x4){0.f, 0.f, 0.f, 0.f};

    const half_t* atile = Ah + (size_t)mb * KB * 4096;
    const half_t* btile = Bh + (size_t)nb * KB * (BN * 32);

    for (int kb = 0; kb < KB; kb += 2) {
        #pragma unroll
        for (int u = 0; u < 2; ++u) {
            const half_t* at = atile + (size_t)(kb + u) * 4096;
            const half_t* bt = btile + (size_t)(kb + u) * (BN * 32);
            #pragma unroll
            for (int v = 0; v < 2; ++v) {
                const int ch = w * 2 + v;
                GLOAD_LDS16(at + ch * 512 + lane * 8, As + u * 4096 + ch * 512);
            }
            GLOAD_LDS16(bt + w * 512 + lane * 8, Bs + u * (BN * 32) + w * 512);
        }
        __syncthreads();

        #pragma unroll
        for (int u = 0; u < 2; ++u) {
            half8 af[MT], bf[NT];
            #pragma unroll
            for (int mt = 0; mt < MT; ++mt)
                af[mt] = *(const half8*)(As + u * 4096
                                         + (wr * (MT * 16) + mt * 16 + l15) * 32 + quad * 8);
            #pragma unroll
            for (int nt = 0; nt < NT; ++nt)
                bf[nt] = *(const half8*)(Bs + u * (BN * 32)
                                         + (wc * 64 + nt * 16 + l15) * 32 + quad * 8);
            #pragma unroll
            for (int mt = 0; mt < MT; ++mt)
                #pragma unroll
                for (int nt = 0; nt < NT; ++nt)
                    acc[mt][nt] = __builtin_amdgcn_mfma_f32_16x16x32_f16(
                        af[mt], bf[nt], acc[mt][nt], 0, 0, 0);
        }
        __syncthreads();
    }

    const int bm = mb * 128, bn = nb * BN;
    #pragma unroll
    for (int nt = 0; nt < NT; ++nt) {
        const int n  = bn + wc * 64 + nt * 16 + l15;
        const float bv = bias[n];
        #pragma unroll
        for (int mt = 0; mt < MT; ++mt) {
            const int m0 = bm + wr * (MT * 16) + mt * 16 + quad * 4;
            #pragma unroll
            for (int rg = 0; rg < 4; ++rg) {
                const float v = acc[mt][nt][rg] + bv;
                if (OUT_HALF) ((half_t*)Cout)[(size_t)(m0 + rg) * N + n] = (half_t)v;
                else          ((float*) Cout)[(size_t)(m0 + rg) * N + n] = v;
            }
        }
    }
}

// ---------------------------------------------------------------------------
// RMSNorm (full 1024) + axial 2D RoPE on the f16 qkv buffer (fp32 math).
// Kf/Vf layouts for the 32-token-chunk, K=32-PV attention (unchanged from v7):
//   chunk c = s>>5 (72 per bh), slot = s&31 within chunk.
//   K slot mapping: tile = (slot>>2)&1, row = 4*(slot>>3)+(slot&3)
//   V: native 16x16x32 A-operand per dt (d = dt*16 + m, k = slot)
//   => softmax outputs {scA[0..3],scB[0..3]} at lane quad q' are exactly
//      slots 8q'..8q'+7, i.e. a contiguous half8 B-operand for K=32 PV.
// ---------------------------------------------------------------------------
__global__ __launch_bounds__(256)
void normrope_v7(half_t* __restrict__ qkvh, const float* __restrict__ q_scale,
                 const float* __restrict__ k_scale, const int* __restrict__ wptr,
                 half_t* __restrict__ Kf, half_t* __restrict__ Vf)
{
    const int token = blockIdx.x;        // b*SS + s
    const int s     = token % SS;
    const int b     = token / SS;
    const int w     = *wptr;
    const int t     = threadIdx.x;
    const float rowp = (float)(s / w);
    const float colp = (float)(s % w);

    half_t* base = qkvh + (size_t)token * 3072;

    const int c    = s >> 5;             // 32-token chunk
    const int slot = s & 31;
    const int ktile = (slot >> 2) & 1;
    const int krow  = ((slot >> 3) << 2) + (slot & 3);

    // ---- V -> Vf (16x16x32 A-operand tiles, k = slot) ----
    {
        half4 v4 = *(const half4*)(base + 2048 + 4 * t);
        const int dabs0 = 4 * t;
        const int h  = dabs0 >> 6;
        const int sl3 = slot >> 3, sl7 = slot & 7;
        half_t* vdst = Vf + ((size_t)(b * HH + h) * 72 + c) * 2048;
        #pragma unroll
        for (int ii = 0; ii < 4; ++ii) {
            const int d = (dabs0 + ii) & 63;
            vdst[(d >> 4) * 512 + (sl3 * 16 + (d & 15)) * 8 + sl7] = v4[ii];
        }
    }

    __shared__ float buf[DIMC];
    __shared__ float red[4];

    #pragma unroll
    for (int sel = 0; sel < 2; ++sel) {
        half_t* row = base + sel * DIMC;
        const float* scp = sel ? k_scale : q_scale;

        half4 xh = *(const half4*)(row + 4 * t);
        float x0 = (float)xh[0], x1 = (float)xh[1], x2 = (float)xh[2], x3 = (float)xh[3];
        float ss = x0 * x0 + x1 * x1 + x2 * x2 + x3 * x3;
        #pragma unroll
        for (int o = 32; o >= 1; o >>= 1) ss += __shfl_xor(ss, o);
        if ((t & 63) == 0) red[t >> 6] = ss;
        __syncthreads();

        const float rinv = rsqrtf((red[0] + red[1] + red[2] + red[3]) * (1.0f / DIMC) + 1e-6f);
        float4 g = *(const float4*)(scp + 4 * t);
        buf[4 * t + 0] = x0 * rinv * g.x;
        buf[4 * t + 1] = x1 * rinv * g.y;
        buf[4 * t + 2] = x2 * rinv * g.z;
        buf[4 * t + 3] = x3 * rinv * g.w;
        __syncthreads();

        const float qsc = sel ? 1.0f : (0.125f * LOG2E);  // log2-domain scores

        #pragma unroll
        for (int pp = 0; pp < 2; ++pp) {
            const int p = t + pp * 256;
            const int h = p >> 5;
            const int r = p & 31;
            const int j = r & 15;
            const float pos = (r < 16) ? rowp : colp;
            const int d1 = (r < 16) ? j : (32 + j);   // within-head dim
            const int d2 = d1 + 16;
            const float freq = exp2f((float)j * -0.83048202372f);
            const float ang  = pos * freq;
            float sn, cs;
            __sincosf(ang, &sn, &cs);
            const float a1 = buf[h * HD + d1], a2 = buf[h * HD + d2];
            const float o1 = (a1 * cs - a2 * sn) * qsc;
            const float o2 = (a2 * cs + a1 * sn) * qsc;
            if (sel == 0) {
                row[h * HD + d1] = (half_t)o1;
                row[h * HD + d2] = (half_t)o2;
            } else {
                half_t* kdst = Kf + ((size_t)(b * HH + h) * 72 + c) * 2048;
                kdst[((ktile << 1) + (d1 >> 5)) * 512
                     + ((((d1 & 31) >> 3) << 4) + krow) * 8 + (d1 & 7)] = (half_t)o1;
                kdst[((ktile << 1) + (d2 >> 5)) * 512
                     + ((((d2 & 31) >> 3) << 4) + krow) * 8 + (d2 & 7)] = (half_t)o2;
            }
        }
        __syncthreads();   // buf/red reused by next sel
    }
}

// ---------------------------------------------------------------------------
// Flash attention v17: v16 (96-row q-tile, 768 blocks = exactly 3/CU, no-max
// softmax, K=32 PV, dist-1 dead-reg prefetch) + l VIA ONES-ROW MFMA.
// Evidence (r10): per-iter 1142 cyc/SIMD vs demand MFMA 350 + VALU 438 +
// trans/loads ~= 93% -- issue-saturated; VALU is the heavier pipe. The 21
// v_add_f32 l-accum ops + end shuffle-reduce move to the matrix pipe:
// onesA = (l15==0 ? 1 : 0) A-frag => D[0][q] = sum_k P[k][q]; l lands in
// acc5[qt][0] at quad==0 exactly where the merge reads (v13-proven).
// -42 VALU cyc/iter/wave for +15 matrix cyc. Registers +13 (~141 unified,
// within the 170 budget of launch_bounds(256,3); revert if WRITE_SIZE grows).
// ---------------------------------------------------------------------------
__global__ __launch_bounds__(256, 3)
void flash_attn_mfma17(const half_t* __restrict__ qkvh, const half_t* __restrict__ Kf,
                       const half_t* __restrict__ Vf, half_t* __restrict__ attn_h)
{
    const int flat = blockIdx.x;         // 0..767, XCD-swizzled
    const int xcd  = flat & 7;
    const int idx  = flat >> 3;          // 0..95  (96 per XCD = exactly 4 bh)
    const int bh   = xcd * 4 + idx / 24;
    const int qtb  = idx % 24;
    const int b    = bh >> 4, h = bh & 15;
    const int t    = threadIdx.x;
    const int w    = t >> 6;
    const int qh   = w >> 1;             // wave's q-half (48 rows)
    const int jt   = w & 1;              // wave's chunk parity
    const int lane = t & 63;
    const int l15  = lane & 15, quad = lane >> 4;

    const size_t tb = (size_t)b * SS;
    const int q0 = qtb * 96;

    __shared__ float mlb[4][48];         // per-wave l for its 48 q's
    __shared__ float Ob[2][64][49];      // [qh][d][q(48)], padded stride 49

    // Q B-frags (loop invariant): B[k=quad*8+i][n=l15], 3 q-tiles x 2 d-groups
    half8 qf[3][2];
    #pragma unroll
    for (int qt = 0; qt < 3; ++qt)
        #pragma unroll
        for (int dg = 0; dg < 2; ++dg)
            qf[qt][dg] = *(const half8*)(qkvh + (tb + q0 + qh * 48 + qt * 16 + l15) * 3072
                                          + h * HD + dg * 32 + quad * 8);

    // ones A-frag: A[m][k] = (m==0). Lane (l15,quad) holds A[l15][quad*8+i].
    const half8 onesA = (l15 == 0)
        ? (half8){(half_t)1, (half_t)1, (half_t)1, (half_t)1,
                  (half_t)1, (half_t)1, (half_t)1, (half_t)1}
        : (half8){(half_t)0, (half_t)0, (half_t)0, (half_t)0,
                  (half_t)0, (half_t)0, (half_t)0, (half_t)0};

    f32x4 acc[4][3];                     // [dt][qt] : O^T[dt*16+quad*4+reg][q]
    f32x4 acc5[3];                       // l-row: acc5[qt][0]@quad0 = l(q=l15)
    #pragma unroll
    for (int qt = 0; qt < 3; ++qt) {
        acc5[qt] = (f32x4){0.f, 0.f, 0.f, 0.f};
        #pragma unroll
        for (int dt = 0; dt < 4; ++dt) acc[dt][qt] = (f32x4){0.f, 0.f, 0.f, 0.f};
    }

    // wave's chunk pointers: wave-chunk p -> global chunk (2p + jt)
    const half_t* kpl = Kf + (size_t)bh * 147456 + jt * 2048 + lane * 8;
    const half_t* vpl = Vf + (size_t)bh * 147456 + jt * 2048 + lane * 8;

    // initial chunk (separate K and V buffers)
    half8 k00 = *(const half8*)(kpl);            // tile0, d 0..31
    half8 k01 = *(const half8*)(kpl + 512);      // tile0, d 32..63
    half8 k10 = *(const half8*)(kpl + 1024);     // tile1, d 0..31
    half8 k11 = *(const half8*)(kpl + 1536);     // tile1, d 32..63
    half8 v0  = *(const half8*)(vpl);            // dt A-frags (k=slot)
    half8 v1  = *(const half8*)(vpl + 512);
    half8 v2  = *(const half8*)(vpl + 1024);
    half8 v3  = *(const half8*)(vpl + 1536);

    const f32x4 initC = (f32x4){-4.f, -4.f, -4.f, -4.f};   // P = exp2(s - 4)

    for (int p = 0; p < 36; ++p) {
        // ---- S^T both 16-row tiles x 3 q-tiles (k regs dead afterwards) ----
        f32x4 scA[3], scB[3];
        __builtin_amdgcn_s_setprio(1);
        #pragma unroll
        for (int qt = 0; qt < 3; ++qt) {
            scA[qt] = initC;
            scA[qt] = __builtin_amdgcn_mfma_f32_16x16x32_f16(k00, qf[qt][0], scA[qt], 0, 0, 0);
            scA[qt] = __builtin_amdgcn_mfma_f32_16x16x32_f16(k01, qf[qt][1], scA[qt], 0, 0, 0);
            scB[qt] = initC;
            scB[qt] = __builtin_amdgcn_mfma_f32_16x16x32_f16(k10, qf[qt][0], scB[qt], 0, 0, 0);
            scB[qt] = __builtin_amdgcn_mfma_f32_16x16x32_f16(k11, qf[qt][1], scB[qt], 0, 0, 0);
        }
        __builtin_amdgcn_s_setprio(0);

        // ---- prefetch next chunk's K into the now-dead k regs ----
        if (p + 1 < 36) {
            const half_t* kN = kpl + (size_t)(p + 1) * 4096;
            k00 = *(const half8*)(kN);
            k01 = *(const half8*)(kN + 512);
            k10 = *(const half8*)(kN + 1024);
            k11 = *(const half8*)(kN + 1536);
        }

        // ---- no-max softmax: P = exp2(s-4) directly (l done by MFMA) ----
        half8 pf[3];
        #pragma unroll
        for (int qt = 0; qt < 3; ++qt) {
            const float a0 = EXP2(scA[qt][0]);
            const float a1 = EXP2(scA[qt][1]);
            const float a2 = EXP2(scA[qt][2]);
            const float a3 = EXP2(scA[qt][3]);
            const float b0 = EXP2(scB[qt][0]);
            const float b1 = EXP2(scB[qt][1]);
            const float b2 = EXP2(scB[qt][2]);
            const float b3 = EXP2(scB[qt][3]);
            // lane quad q' holds P for slots 8q'..8q'+7 -> contiguous B-frag
            pf[qt] = (half8){(half_t)a0, (half_t)a1, (half_t)a2, (half_t)a3,
                             (half_t)b0, (half_t)b1, (half_t)b2, (half_t)b3};
        }

        // ---- O^T += V^T.P^T ; l-row += 1.P^T (v regs dead afterwards) ----
        __builtin_amdgcn_s_setprio(1);
        #pragma unroll
        for (int dt = 0; dt < 4; ++dt) {
            const half8 vf = (dt == 0) ? v0 : (dt == 1) ? v1 : (dt == 2) ? v2 : v3;
            #pragma unroll
            for (int qt = 0; qt < 3; ++qt)
                acc[dt][qt] = __builtin_amdgcn_mfma_f32_16x16x32_f16(
                    vf, pf[qt], acc[dt][qt], 0, 0, 0);
        }
        #pragma unroll
        for (int qt = 0; qt < 3; ++qt)
            acc5[qt] = __builtin_amdgcn_mfma_f32_16x16x32_f16(
                onesA, pf[qt], acc5[qt], 0, 0, 0);
        __builtin_amdgcn_s_setprio(0);

        // ---- prefetch next chunk's V into the now-dead v regs ----
        if (p + 1 < 36) {
            const half_t* vN = vpl + (size_t)(p + 1) * 4096;
            v0 = *(const half8*)(vN);
            v1 = *(const half8*)(vN + 512);
            v2 = *(const half8*)(vN + 1024);
            v3 = *(const half8*)(vN + 1536);
        }
    }

    // ---- 2-way merge across jt waves, per q-half (l from acc5 row 0) ----
    #pragma unroll
    for (int qt = 0; qt < 3; ++qt)
        if (quad == 0) mlb[w][qt * 16 + l15] = acc5[qt][0];
    __syncthreads();

    float fac[3];
    #pragma unroll
    for (int qt = 0; qt < 3; ++qt) {
        const int q = qt * 16 + l15;
        fac[qt] = 1.0f / (mlb[qh * 2 + 0][q] + mlb[qh * 2 + 1][q]);
    }

    #pragma unroll
    for (int ph = 0; ph < 2; ++ph) {
        if (jt == ph) {
            #pragma unroll
            for (int dt = 0; dt < 4; ++dt)
                #pragma unroll
                for (int qt = 0; qt < 3; ++qt)
                    #pragma unroll
                    for (int rg = 0; rg < 4; ++rg) {
                        const int d = dt * 16 + quad * 4 + rg;
                        const int q = qt * 16 + l15;
                        const float v = acc[dt][qt][rg] * fac[qt];
                        if (ph == 0) Ob[qh][d][q] = v;
                        else         Ob[qh][d][q] += v;
                    }
        }
        __syncthreads();
    }

    // ---- store O as f16, tile-blocked [mb][kb][128][32] for the proj GEMM ----
    // 96 rows x 64 d = 6144 halfs; 3 groups of 32 rows, 8 threads/row x 8 d.
    #pragma unroll
    for (int g2 = 0; g2 < 3; ++g2) {
        const int q  = g2 * 32 + (t >> 3);   // 0..95
        const int ds = (t & 7) * 8;          // 0..56, 8-aligned
        const int qh2 = (q >= 48) ? 1 : 0;
        const int qq  = q - 48 * qh2;
        const size_t mrow = tb + q0 + q;
        const int mb2 = (int)(mrow >> 7);
        const int mm  = (int)(mrow & 127);
        const int kb2 = (h * HD + ds) >> 5;
        const int kk  = ds & 31;
        half8 o;
        #pragma unroll
        for (int ii = 0; ii < 8; ++ii) o[ii] = (half_t)Ob[qh2][ds + ii][qq];
        *(half8*)(attn_h + ((size_t)mb2 * 32 + kb2) * 4096 + mm * 32 + kk) = o;
    }
}

// ---------------------------------------------------------------------------
// Launch
// ---------------------------------------------------------------------------
extern "C" void kernel_launch(void* const* d_in, const int* in_sizes, int n_in,
                              void* d_out, int out_size, void* d_ws, size_t ws_size,
                              hipStream_t stream)
{
    const float* input   = (const float*)d_in[0];
    const float* qkv_w   = (const float*)d_in[1];
    const float* qkv_b   = (const float*)d_in[2];
    const float* q_scale = (const float*)d_in[3];
    const float* k_scale = (const float*)d_in[4];
    const float* proj_w  = (const float*)d_in[5];
    const float* proj_b  = (const float*)d_in[6];
    const int*   width   = (const int*)d_in[8];
    float* out = (float*)d_out;

    // ws layout (all f16): qkv_h 28.3MB | attn_h 9.4 | Vf 9.4 | Ah 9.4 (reused
    // as Kf after GEMM1) | Bh1 6.3 | Bh2 2.1  => 65.0 MB total
    half_t* qkvh   = (half_t*)d_ws;
    half_t* attn_h = qkvh   + (size_t)4608 * 3072;
    half_t* Vf     = attn_h + (size_t)4608 * 1024;
    half_t* Ah     = Vf     + (size_t)32 * 72 * 2048;
    half_t* Bh1    = Ah     + (size_t)4608 * 1024;
    half_t* Bh2    = Bh1    + (size_t)3072 * 1024;
    half_t* Kf     = Ah;    // Ah is dead after GEMM1; Kf is written by normrope

    const int M = BB * SS;   // 4608

    // 0) fp32 -> f16 tile-blocked converters
    convert_tile_f16<192><<<dim3(M / 192, DINC / 32),        256, 0, stream>>>(input,  Ah,  DINC);
    convert_tile_f16<96><<<dim3(3 * DIMC / 96, DINC / 32),   256, 0, stream>>>(qkv_w, Bh1, DINC);
    convert_tile_f16<64><<<dim3(DINC / 64, DIMC / 32),       256, 0, stream>>>(proj_w, Bh2, DIMC);

    // 1) qkv_h = f16( input @ qkv_w^T + qkv_b )  -- 192x96 tiles, 768 blocks
    gemm_mfma192<<<dim3(3 * DIMC / 96, M / 192), 256, 0, stream>>>(
        Ah, Bh1, qkv_b, qkvh);

    // 2) RMSNorm + RoPE: Q in place (log2-scaled), K -> Kf, V -> Vf
    normrope_v7<<<M, 256, 0, stream>>>(qkvh, q_scale, k_scale, width, Kf, Vf);

    // 3) MFMA flash attention -> attn_h (f16, tile-blocked), XCD-swizzled
    flash_attn_mfma17<<<dim3(768), 256, 0, stream>>>(qkvh, Kf, Vf, attn_h);

    // 4) out = attn @ proj_w^T + proj_b  (fp32 out, BN=64 for occupancy)
    gemm_mfma<64, false><<<dim3(DINC / 64, M / 128), 256, 0, stream>>>(
        attn_h, Bh2, proj_b, out, M, DINC, DIMC);
}